// Round 1
// baseline (1083.584 us; speedup 1.0000x reference)
//
#include <hip/hip_runtime.h>
#include <math.h>

#define NB 256
#define SEQ 65536
#define NP 2047
#define NPM 2046
#define LEN1 2047
#define LEN2 1023
#define LEN3 511
#define C1 32
#define C2 64
#define C3 128

// workspace offsets (in floats)
#define OFF_X3   0
#define SZ_X3    (NB*3*NP)
#define OFF_DMAX (OFF_X3 + SZ_X3)
#define SZ_DMAX  (NB*NPM)
#define OFF_Y1   (OFF_DMAX + SZ_DMAX)
#define SZ_Y1    (NB*C1*LEN1)
#define OFF_Y2   (OFF_Y1 + SZ_Y1)
#define SZ_Y2    (NB*C2*LEN2)
#define OFF_PART (OFF_Y2 + SZ_Y2)
#define SZ_PART  (C3*NB*2)
#define OFF_S1   (OFF_PART + SZ_PART)
#define OFF_S2   (OFF_S1 + 2*C1)
#define OFF_S3   (OFF_S2 + 2*C2)
#define OFF_Y3   OFF_Y1   // y1 dead after conv2; reuse for y3

// ---------------- K1: patch mean/std + dmax ----------------
__global__ __launch_bounds__(256) void k_patch(const float* __restrict__ x, float* __restrict__ ws){
  float* x3   = ws + OFF_X3;
  float* dmax = ws + OFF_DMAX;
  int wid  = blockIdx.x*4 + (threadIdx.x>>6);
  int lane = threadIdx.x & 63;
  int b = wid / NP;
  int p = wid - b*NP;
  const float* xb = x + (size_t)b*SEQ + p*32 + lane;
  float v  = xb[0];
  float v2 = (p < NPM) ? xb[32] : v;
  float s = v, q = v*v, d = v2 - v;
  #pragma unroll
  for (int off=32; off; off>>=1){
    s += __shfl_xor(s, off, 64);
    q += __shfl_xor(q, off, 64);
    d  = fmaxf(d, __shfl_xor(d, off, 64));
  }
  if (lane == 0){
    float mean = s * (1.0f/64.0f);
    float var  = (q - s*mean) * (1.0f/63.0f);   // ddof=1
    x3[(b*3+0)*NP + p] = mean;
    x3[(b*3+1)*NP + p] = sqrtf(fmaxf(var, 0.0f));
    if (p < NPM) dmax[b*NPM + p] = d;
  }
}

// ---------------- K0: init x3 channel 2 with conv1_b ----------------
__global__ __launch_bounds__(256) void k_initc2(const float* __restrict__ c1b, float* __restrict__ ws){
  int i = blockIdx.x*256 + threadIdx.x;
  if (i < NB*NP){
    int b = i / NP; int o = i - b*NP;
    ws[OFF_X3 + (b*3+2)*NP + o] = c1b[o];
  }
}

// ---------------- K2: d2[b,o] += sum_k dmax[b,k]*W[o,k]  (split-K sgemm) ----------------
__global__ __launch_bounds__(256) void k_gemm(const float* __restrict__ W, float* __restrict__ ws){
  const float* A = ws + OFF_DMAX;     // [NB][NPM]
  float* x3 = ws + OFF_X3;
  __shared__ float As[16][65];
  __shared__ float Bs[16][65];
  int tid = threadIdx.x;
  int o0 = blockIdx.x * 64;
  int b0 = blockIdx.y * 64;
  int ks = blockIdx.z * 256;
  int ke = min(ks + 256, NPM);
  int tx = tid & 15, ty = tid >> 4;
  float acc[4][4];
  #pragma unroll
  for (int m=0;m<4;m++){
    #pragma unroll
    for (int n=0;n<4;n++) acc[m][n]=0.f;
  }
  int lr = tid >> 2;
  int lc = (tid & 3) * 4;
  for (int kk = ks; kk < ke; kk += 16){
    int rem = ke - kk;
    {
      const float* ap = A + (b0+lr)*NPM + kk + lc;
      #pragma unroll
      for (int j=0;j<4;j++) As[lc+j][lr] = (lc+j < rem) ? ap[j] : 0.f;
    }
    {
      int orow = o0 + lr;
      const float* wp = W + (size_t)orow*NPM + kk + lc;
      #pragma unroll
      for (int j=0;j<4;j++) Bs[lc+j][lr] = (orow < NP && lc+j < rem) ? wp[j] : 0.f;
    }
    __syncthreads();
    #pragma unroll
    for (int k=0;k<16;k++){
      float a[4], w[4];
      #pragma unroll
      for (int m=0;m<4;m++) a[m] = As[k][ty*4+m];
      #pragma unroll
      for (int n=0;n<4;n++) w[n] = Bs[k][tx*4+n];
      #pragma unroll
      for (int m=0;m<4;m++){
        #pragma unroll
        for (int n=0;n<4;n++) acc[m][n] = fmaf(a[m], w[n], acc[m][n]);
      }
    }
    __syncthreads();
  }
  #pragma unroll
  for (int m=0;m<4;m++){
    int b = b0 + ty*4 + m;
    #pragma unroll
    for (int n=0;n<4;n++){
      int o = o0 + tx*4 + n;
      if (o < NP) atomicAdd(&x3[(b*3+2)*NP + o], acc[m][n]);
    }
  }
}

// ---------------- K3: conv1 (3->32, k=5, pad=2) ----------------
__global__ __launch_bounds__(256) void k_conv1(const float* __restrict__ w1, const float* __restrict__ b1, float* __restrict__ ws){
  const float* x3 = ws + OFF_X3;
  float* y1 = ws + OFF_Y1;
  int b = blockIdx.y;
  int l = blockIdx.x*256 + threadIdx.x;
  bool valid = (l < LEN1);
  float xin[3][5];
  #pragma unroll
  for (int i=0;i<3;i++){
    #pragma unroll
    for (int j=0;j<5;j++){
      int t = l + j - 2;
      xin[i][j] = (valid && t >= 0 && t < LEN1) ? x3[(b*3+i)*NP + t] : 0.f;
    }
  }
  for (int c=0;c<C1;c++){
    float a = b1[c];
    #pragma unroll
    for (int i=0;i<3;i++){
      #pragma unroll
      for (int j=0;j<5;j++) a = fmaf(w1[(c*3+i)*5+j], xin[i][j], a);
    }
    if (valid) y1[(b*C1+c)*LEN1 + l] = a;
  }
}

// ---------------- stats: per-(b,c) partial sum/sumsq ----------------
__global__ __launch_bounds__(256) void k_stats(const float* __restrict__ y, float* __restrict__ part, int C, int L){
  int b = blockIdx.x, c = blockIdx.y;
  const float* p = y + ((size_t)b*C + c)*L;
  float s=0.f, q=0.f;
  for (int i=threadIdx.x; i<L; i+=256){ float v=p[i]; s+=v; q=fmaf(v,v,q); }
  __shared__ float rs[4], rq[4];
  #pragma unroll
  for (int off=32; off; off>>=1){ s += __shfl_xor(s,off,64); q += __shfl_xor(q,off,64); }
  int wid = threadIdx.x>>6, lane = threadIdx.x&63;
  if (lane==0){ rs[wid]=s; rq[wid]=q; }
  __syncthreads();
  if (threadIdx.x==0){
    part[(c*NB+b)*2+0] = rs[0]+rs[1]+rs[2]+rs[3];
    part[(c*NB+b)*2+1] = rq[0]+rq[1]+rq[2]+rq[3];
  }
}

// ---------------- finalize BN: stats[c]=g*rsqrt(var+eps), stats[C+c]=be-mean*scale ----------------
__global__ __launch_bounds__(256) void k_fin(const float* __restrict__ part, const float* __restrict__ g,
                                             const float* __restrict__ be, float* __restrict__ stats,
                                             int C, double invN){
  int c = blockIdx.x;
  float s = part[(c*NB+threadIdx.x)*2+0];
  float q = part[(c*NB+threadIdx.x)*2+1];
  #pragma unroll
  for (int off=32; off; off>>=1){ s += __shfl_xor(s,off,64); q += __shfl_xor(q,off,64); }
  __shared__ float rs[4], rq[4];
  int wid = threadIdx.x>>6, lane=threadIdx.x&63;
  if (lane==0){ rs[wid]=s; rq[wid]=q; }
  __syncthreads();
  if (threadIdx.x==0){
    double S = (double)rs[0]+rs[1]+rs[2]+rs[3];
    double Q = (double)rq[0]+rq[1]+rq[2]+rq[3];
    double mean = S*invN;
    double var  = Q*invN - mean*mean;
    double a = (double)g[c] / sqrt(var + 1e-5);
    stats[c]   = (float)a;
    stats[C+c] = (float)((double)be[c] - mean*a);
  }
}

// ---------------- K5: bn1+relu+pool + conv2 (32->64, k=3, pad=1) ----------------
__global__ __launch_bounds__(256) void k_conv2(const float* __restrict__ w2, const float* __restrict__ b2, float* __restrict__ ws){
  const float* y1 = ws + OFF_Y1;
  const float* st = ws + OFF_S1;
  float* y2 = ws + OFF_Y2;
  int b = blockIdx.y;
  int l0 = blockIdx.x*256;
  __shared__ float h[C1][260];
  __shared__ float sa[C1], sb[C1];
  if (threadIdx.x < C1){ sa[threadIdx.x]=st[threadIdx.x]; sb[threadIdx.x]=st[C1+threadIdx.x]; }
  __syncthreads();
  for (int idx=threadIdx.x; idx<C1*258; idx+=256){
    int i = idx/258, mm = idx - i*258;
    int m = mm + l0 - 1;
    float v = 0.f;
    if (m>=0 && m<LEN2){
      const float* p = y1 + (b*C1+i)*LEN1 + 2*m;
      float v0 = fmaf(sa[i], p[0], sb[i]);
      float v1 = fmaf(sa[i], p[1], sb[i]);
      v = fmaxf(fmaxf(v0,v1), 0.f);
    }
    h[i][mm] = v;
  }
  __syncthreads();
  int l = l0 + threadIdx.x;
  float acc[C2];
  #pragma unroll
  for (int c=0;c<C2;c++) acc[c] = b2[c];
  for (int i=0;i<C1;i++){
    float hm = h[i][threadIdx.x], h0 = h[i][threadIdx.x+1], hp = h[i][threadIdx.x+2];
    #pragma unroll
    for (int c=0;c<C2;c++){
      const float* wp = w2 + (c*C1+i)*3;   // wave-uniform -> s_load
      acc[c] = fmaf(wp[0], hm, acc[c]);
      acc[c] = fmaf(wp[1], h0, acc[c]);
      acc[c] = fmaf(wp[2], hp, acc[c]);
    }
  }
  if (l < LEN2){
    #pragma unroll
    for (int c=0;c<C2;c++) y2[(b*C2+c)*LEN2 + l] = acc[c];
  }
}

// ---------------- K7: bn2+relu+pool + conv3 (64->128, k=3, pad=1) ----------------
__global__ __launch_bounds__(256) void k_conv3(const float* __restrict__ w3, const float* __restrict__ b3, float* __restrict__ ws){
  const float* y2 = ws + OFF_Y2;
  const float* st = ws + OFF_S2;
  float* y3 = ws + OFF_Y3;
  int b = blockIdx.y;
  int l0 = blockIdx.x*128;
  __shared__ float h[C2][132];
  __shared__ float sa[C2], sb[C2];
  if (threadIdx.x < C2){ sa[threadIdx.x]=st[threadIdx.x]; sb[threadIdx.x]=st[C2+threadIdx.x]; }
  __syncthreads();
  for (int idx=threadIdx.x; idx<C2*130; idx+=256){
    int i = idx/130, mm = idx - i*130;
    int m = mm + l0 - 1;
    float v=0.f;
    if (m>=0 && m<LEN3){
      const float* p = y2 + (b*C2+i)*LEN2 + 2*m;
      float v0 = fmaf(sa[i], p[0], sb[i]);
      float v1 = fmaf(sa[i], p[1], sb[i]);
      v = fmaxf(fmaxf(v0,v1), 0.f);
    }
    h[i][mm] = v;
  }
  __syncthreads();
  int lhalf = threadIdx.x >> 7;      // wave-uniform (waves 0,1 -> half 0; waves 2,3 -> half 1)
  int lt = threadIdx.x & 127;
  int l = l0 + lt;
  int cbase = lhalf * 64;
  float acc[64];
  #pragma unroll
  for (int c=0;c<64;c++) acc[c] = b3[cbase+c];
  for (int i=0;i<C2;i++){
    float hm = h[i][lt], h0 = h[i][lt+1], hp = h[i][lt+2];
    #pragma unroll
    for (int c=0;c<64;c++){
      const float* wp = w3 + ((cbase+c)*C2+i)*3;   // wave-uniform -> s_load
      acc[c] = fmaf(wp[0], hm, acc[c]);
      acc[c] = fmaf(wp[1], h0, acc[c]);
      acc[c] = fmaf(wp[2], hp, acc[c]);
    }
  }
  if (l < LEN3){
    #pragma unroll
    for (int c=0;c<64;c++) y3[(b*C3+cbase+c)*LEN3 + l] = acc[c];
  }
}

// ---------------- K9: bn3+relu+mean ----------------
__global__ __launch_bounds__(256) void k_out(float* __restrict__ out, const float* __restrict__ ws){
  const float* y3 = ws + OFF_Y3;
  const float* st = ws + OFF_S3;
  int w = blockIdx.x*4 + (threadIdx.x>>6);
  int lane = threadIdx.x & 63;
  int b = w >> 7, c = w & 127;
  const float* p = y3 + (b*C3+c)*LEN3;
  float a = st[c], sh = st[C3+c];
  float s = 0.f;
  for (int i=lane; i<LEN3; i+=64) s += fmaxf(fmaf(a, p[i], sh), 0.f);
  #pragma unroll
  for (int off=32; off; off>>=1) s += __shfl_xor(s,off,64);
  if (lane==0) out[b*C3+c] = s * (1.0f/511.0f);
}

extern "C" void kernel_launch(void* const* d_in, const int* in_sizes, int n_in,
                              void* d_out, int out_size, void* d_ws, size_t ws_size,
                              hipStream_t stream) {
  const float* x   = (const float*)d_in[0];
  const float* c1w = (const float*)d_in[1];
  const float* c1b = (const float*)d_in[2];
  const float* w1  = (const float*)d_in[3];
  const float* b1  = (const float*)d_in[4];
  const float* g1  = (const float*)d_in[5];
  const float* be1 = (const float*)d_in[6];
  const float* w2  = (const float*)d_in[7];
  const float* b2  = (const float*)d_in[8];
  const float* g2  = (const float*)d_in[9];
  const float* be2 = (const float*)d_in[10];
  const float* w3  = (const float*)d_in[11];
  const float* b3  = (const float*)d_in[12];
  const float* g3  = (const float*)d_in[13];
  const float* be3 = (const float*)d_in[14];
  float* ws  = (float*)d_ws;
  float* out = (float*)d_out;

  hipLaunchKernelGGL(k_patch,  dim3((NB*NP)/4), dim3(256), 0, stream, x, ws);
  hipLaunchKernelGGL(k_initc2, dim3((NB*NP+255)/256), dim3(256), 0, stream, c1b, ws);
  hipLaunchKernelGGL(k_gemm,   dim3(32,4,8), dim3(256), 0, stream, c1w, ws);
  hipLaunchKernelGGL(k_conv1,  dim3(8,NB), dim3(256), 0, stream, w1, b1, ws);
  hipLaunchKernelGGL(k_stats,  dim3(NB,C1), dim3(256), 0, stream, ws+OFF_Y1, ws+OFF_PART, C1, LEN1);
  hipLaunchKernelGGL(k_fin,    dim3(C1), dim3(256), 0, stream, ws+OFF_PART, g1, be1, ws+OFF_S1, C1, 1.0/((double)NB*LEN1));
  hipLaunchKernelGGL(k_conv2,  dim3(4,NB), dim3(256), 0, stream, w2, b2, ws);
  hipLaunchKernelGGL(k_stats,  dim3(NB,C2), dim3(256), 0, stream, ws+OFF_Y2, ws+OFF_PART, C2, LEN2);
  hipLaunchKernelGGL(k_fin,    dim3(C2), dim3(256), 0, stream, ws+OFF_PART, g2, be2, ws+OFF_S2, C2, 1.0/((double)NB*LEN2));
  hipLaunchKernelGGL(k_conv3,  dim3(4,NB), dim3(256), 0, stream, w3, b3, ws);
  hipLaunchKernelGGL(k_stats,  dim3(NB,C3), dim3(256), 0, stream, ws+OFF_Y3, ws+OFF_PART, C3, LEN3);
  hipLaunchKernelGGL(k_fin,    dim3(C3), dim3(256), 0, stream, ws+OFF_PART, g3, be3, ws+OFF_S3, C3, 1.0/((double)NB*LEN3));
  hipLaunchKernelGGL(k_out,    dim3((NB*C3)/4), dim3(256), 0, stream, out, ws);
}

// Round 2
// 813.161 us; speedup vs baseline: 1.3326x; 1.3326x over previous
//
#include <hip/hip_runtime.h>
#include <math.h>

#define NB 256
#define SEQ 65536
#define NP 2047
#define NPM 2046
#define LEN1 2047
#define LEN2 1023
#define LEN3 511
#define C1 32
#define C2 64
#define C3 128

// workspace offsets (in floats)
#define OFF_X3   0
#define SZ_X3    (NB*3*NP)
#define OFF_DMAX (OFF_X3 + SZ_X3)
#define SZ_DMAX  (NB*NPM)
#define OFF_Y1   (OFF_DMAX + SZ_DMAX)
#define SZ_Y1    (NB*C1*LEN1)
#define OFF_Y2   (OFF_Y1 + SZ_Y1)
#define SZ_Y2    (NB*C2*LEN2)
#define OFF_PART (OFF_Y2 + SZ_Y2)
#define SZ_PART  (C3*NB*2)
#define OFF_S1   (OFF_PART + SZ_PART)
#define OFF_S2   (OFF_S1 + 2*C1)
#define OFF_S3   (OFF_S2 + 2*C2)
#define OFF_Y3   OFF_Y1   // y1 dead after conv2; reuse for y3

// ---------------- K1: patch mean/std + dmax ----------------
__global__ __launch_bounds__(256) void k_patch(const float* __restrict__ x, float* __restrict__ ws){
  float* x3   = ws + OFF_X3;
  float* dmax = ws + OFF_DMAX;
  int wid  = blockIdx.x*4 + (threadIdx.x>>6);
  int lane = threadIdx.x & 63;
  int b = wid / NP;
  int p = wid - b*NP;
  const float* xb = x + (size_t)b*SEQ + p*32 + lane;
  float v  = xb[0];
  float v2 = (p < NPM) ? xb[32] : v;
  float s = v, q = v*v, d = v2 - v;
  #pragma unroll
  for (int off=32; off; off>>=1){
    s += __shfl_xor(s, off, 64);
    q += __shfl_xor(q, off, 64);
    d  = fmaxf(d, __shfl_xor(d, off, 64));
  }
  if (lane == 0){
    float mean = s * (1.0f/64.0f);
    float var  = (q - s*mean) * (1.0f/63.0f);   // ddof=1
    x3[(b*3+0)*NP + p] = mean;
    x3[(b*3+1)*NP + p] = sqrtf(fmaxf(var, 0.0f));
    if (p < NPM) dmax[b*NPM + p] = d;
  }
}

// ---------------- K0: init x3 channel 2 with conv1_b ----------------
__global__ __launch_bounds__(256) void k_initc2(const float* __restrict__ c1b, float* __restrict__ ws){
  int i = blockIdx.x*256 + threadIdx.x;
  if (i < NB*NP){
    int b = i / NP; int o = i - b*NP;
    ws[OFF_X3 + (b*3+2)*NP + o] = c1b[o];
  }
}

// ---------------- K2: d2[b,o] += sum_k dmax[b,k]*W[o,k]  (split-K sgemm) ----------------
__global__ __launch_bounds__(256) void k_gemm(const float* __restrict__ W, float* __restrict__ ws){
  const float* A = ws + OFF_DMAX;     // [NB][NPM]
  float* x3 = ws + OFF_X3;
  __shared__ float As[16][65];
  __shared__ float Bs[16][65];
  int tid = threadIdx.x;
  int o0 = blockIdx.x * 64;
  int b0 = blockIdx.y * 64;
  int ks = blockIdx.z * 256;
  int ke = min(ks + 256, NPM);
  int tx = tid & 15, ty = tid >> 4;
  float acc[4][4];
  #pragma unroll
  for (int m=0;m<4;m++){
    #pragma unroll
    for (int n=0;n<4;n++) acc[m][n]=0.f;
  }
  int lr = tid >> 2;
  int lc = (tid & 3) * 4;
  for (int kk = ks; kk < ke; kk += 16){
    int rem = ke - kk;
    {
      const float* ap = A + (b0+lr)*NPM + kk + lc;
      #pragma unroll
      for (int j=0;j<4;j++) As[lc+j][lr] = (lc+j < rem) ? ap[j] : 0.f;
    }
    {
      int orow = o0 + lr;
      const float* wp = W + (size_t)orow*NPM + kk + lc;
      #pragma unroll
      for (int j=0;j<4;j++) Bs[lc+j][lr] = (orow < NP && lc+j < rem) ? wp[j] : 0.f;
    }
    __syncthreads();
    #pragma unroll
    for (int k=0;k<16;k++){
      float a[4], w[4];
      #pragma unroll
      for (int m=0;m<4;m++) a[m] = As[k][ty*4+m];
      #pragma unroll
      for (int n=0;n<4;n++) w[n] = Bs[k][tx*4+n];
      #pragma unroll
      for (int m=0;m<4;m++){
        #pragma unroll
        for (int n=0;n<4;n++) acc[m][n] = fmaf(a[m], w[n], acc[m][n]);
      }
    }
    __syncthreads();
  }
  #pragma unroll
  for (int m=0;m<4;m++){
    int b = b0 + ty*4 + m;
    #pragma unroll
    for (int n=0;n<4;n++){
      int o = o0 + tx*4 + n;
      if (o < NP) atomicAdd(&x3[(b*3+2)*NP + o], acc[m][n]);
    }
  }
}

// ---------------- K3: conv1 (3->32, k=5, pad=2) ----------------
__global__ __launch_bounds__(256) void k_conv1(const float* __restrict__ w1, const float* __restrict__ b1, float* __restrict__ ws){
  const float* x3 = ws + OFF_X3;
  float* y1 = ws + OFF_Y1;
  int b = blockIdx.y;
  int l = blockIdx.x*256 + threadIdx.x;
  bool valid = (l < LEN1);
  float xin[3][5];
  #pragma unroll
  for (int i=0;i<3;i++){
    #pragma unroll
    for (int j=0;j<5;j++){
      int t = l + j - 2;
      xin[i][j] = (valid && t >= 0 && t < LEN1) ? x3[(b*3+i)*NP + t] : 0.f;
    }
  }
  #pragma unroll 8
  for (int c=0;c<C1;c++){
    float a = b1[c];
    #pragma unroll
    for (int i=0;i<3;i++){
      #pragma unroll
      for (int j=0;j<5;j++) a = fmaf(w1[(c*3+i)*5+j], xin[i][j], a);
    }
    if (valid) y1[(b*C1+c)*LEN1 + l] = a;
  }
}

// ---------------- stats: per-(b,c) partial sum/sumsq ----------------
__global__ __launch_bounds__(256) void k_stats(const float* __restrict__ y, float* __restrict__ part, int C, int L){
  int b = blockIdx.x, c = blockIdx.y;
  const float* p = y + ((size_t)b*C + c)*L;
  float s=0.f, q=0.f;
  for (int i=threadIdx.x; i<L; i+=256){ float v=p[i]; s+=v; q=fmaf(v,v,q); }
  __shared__ float rs[4], rq[4];
  #pragma unroll
  for (int off=32; off; off>>=1){ s += __shfl_xor(s,off,64); q += __shfl_xor(q,off,64); }
  int wid = threadIdx.x>>6, lane = threadIdx.x&63;
  if (lane==0){ rs[wid]=s; rq[wid]=q; }
  __syncthreads();
  if (threadIdx.x==0){
    part[(c*NB+b)*2+0] = rs[0]+rs[1]+rs[2]+rs[3];
    part[(c*NB+b)*2+1] = rq[0]+rq[1]+rq[2]+rq[3];
  }
}

// ---------------- finalize BN: stats[c]=g*rsqrt(var+eps), stats[C+c]=be-mean*scale ----------------
__global__ __launch_bounds__(256) void k_fin(const float* __restrict__ part, const float* __restrict__ g,
                                             const float* __restrict__ be, float* __restrict__ stats,
                                             int C, double invN){
  int c = blockIdx.x;
  float s = part[(c*NB+threadIdx.x)*2+0];
  float q = part[(c*NB+threadIdx.x)*2+1];
  #pragma unroll
  for (int off=32; off; off>>=1){ s += __shfl_xor(s,off,64); q += __shfl_xor(q,off,64); }
  __shared__ float rs[4], rq[4];
  int wid = threadIdx.x>>6, lane=threadIdx.x&63;
  if (lane==0){ rs[wid]=s; rq[wid]=q; }
  __syncthreads();
  if (threadIdx.x==0){
    double S = (double)rs[0]+rs[1]+rs[2]+rs[3];
    double Q = (double)rq[0]+rq[1]+rq[2]+rq[3];
    double mean = S*invN;
    double var  = Q*invN - mean*mean;
    double a = (double)g[c] / sqrt(var + 1e-5);
    stats[c]   = (float)a;
    stats[C+c] = (float)((double)be[c] - mean*a);
  }
}

// ---------------- K5: bn1+relu+pool + conv2 (32->64, k=3, pad=1) ----------------
// 4 waves x 16 ch (all 64 out-ch), 64 positions per block.
// Channel group wave-uniform via readfirstlane -> weight/bias loads are s_load.
__global__ __launch_bounds__(256) void k_conv2(const float* __restrict__ w2, const float* __restrict__ b2, float* __restrict__ ws){
  const float* y1 = ws + OFF_Y1;
  const float* st = ws + OFF_S1;
  float* y2 = ws + OFF_Y2;
  int b = blockIdx.y;
  int l0 = blockIdx.x*64;
  __shared__ float h[C1][66];
  __shared__ float sa[C1], sb[C1];
  if (threadIdx.x < C1){ sa[threadIdx.x]=st[threadIdx.x]; sb[threadIdx.x]=st[C1+threadIdx.x]; }
  __syncthreads();
  for (int idx=threadIdx.x; idx<C1*66; idx+=256){
    int i = idx/66, mm = idx - i*66;
    int m = mm + l0 - 1;
    float v = 0.f;
    if (m>=0 && m<LEN2){
      const float* p = y1 + (b*C1+i)*LEN1 + 2*m;
      float v0 = fmaf(sa[i], p[0], sb[i]);
      float v1 = fmaf(sa[i], p[1], sb[i]);
      v = fmaxf(fmaxf(v0,v1), 0.f);
    }
    h[i][mm] = v;
  }
  __syncthreads();
  int grp  = __builtin_amdgcn_readfirstlane(threadIdx.x >> 6);  // 0..3, wave-uniform
  int lt   = threadIdx.x & 63;
  int cbase = grp * 16;
  int l = l0 + lt;
  float acc[16];
  #pragma unroll
  for (int c=0;c<16;c++) acc[c] = b2[cbase+c];
  for (int i=0;i<C1;i++){
    float hm = h[i][lt], h0 = h[i][lt+1], hp = h[i][lt+2];
    #pragma unroll
    for (int c=0;c<16;c++){
      const float* wp = w2 + ((cbase+c)*C1+i)*3;   // scalar address -> s_load
      acc[c] = fmaf(wp[0], hm, acc[c]);
      acc[c] = fmaf(wp[1], h0, acc[c]);
      acc[c] = fmaf(wp[2], hp, acc[c]);
    }
  }
  if (l < LEN2){
    #pragma unroll
    for (int c=0;c<16;c++) y2[(b*C2+cbase+c)*LEN2 + l] = acc[c];
  }
}

// ---------------- K7: bn2+relu+pool + conv3 (64->128, k=3, pad=1) ----------------
// grid.y = channel half (64 ch each); 4 waves x 16 ch, 64 positions per block.
__global__ __launch_bounds__(256) void k_conv3(const float* __restrict__ w3, const float* __restrict__ b3, float* __restrict__ ws){
  const float* y2 = ws + OFF_Y2;
  const float* st = ws + OFF_S2;
  float* y3 = ws + OFF_Y3;
  int b = blockIdx.z;
  int zc = blockIdx.y;           // 0 or 1: which 64-channel half
  int l0 = blockIdx.x*64;
  __shared__ float h[C2][66];
  __shared__ float sa[C2], sb[C2];
  if (threadIdx.x < C2){ sa[threadIdx.x]=st[threadIdx.x]; sb[threadIdx.x]=st[C2+threadIdx.x]; }
  __syncthreads();
  for (int idx=threadIdx.x; idx<C2*66; idx+=256){
    int i = idx/66, mm = idx - i*66;
    int m = mm + l0 - 1;
    float v=0.f;
    if (m>=0 && m<LEN3){
      const float* p = y2 + (b*C2+i)*LEN2 + 2*m;
      float v0 = fmaf(sa[i], p[0], sb[i]);
      float v1 = fmaf(sa[i], p[1], sb[i]);
      v = fmaxf(fmaxf(v0,v1), 0.f);
    }
    h[i][mm] = v;
  }
  __syncthreads();
  int grp  = __builtin_amdgcn_readfirstlane(threadIdx.x >> 6);  // 0..3, wave-uniform
  int lt   = threadIdx.x & 63;
  int cbase = zc*64 + grp*16;
  int l = l0 + lt;
  float acc[16];
  #pragma unroll
  for (int c=0;c<16;c++) acc[c] = b3[cbase+c];
  for (int i=0;i<C2;i++){
    float hm = h[i][lt], h0 = h[i][lt+1], hp = h[i][lt+2];
    #pragma unroll
    for (int c=0;c<16;c++){
      const float* wp = w3 + ((cbase+c)*C2+i)*3;   // scalar address -> s_load
      acc[c] = fmaf(wp[0], hm, acc[c]);
      acc[c] = fmaf(wp[1], h0, acc[c]);
      acc[c] = fmaf(wp[2], hp, acc[c]);
    }
  }
  if (l < LEN3){
    #pragma unroll
    for (int c=0;c<16;c++) y3[(b*C3+cbase+c)*LEN3 + l] = acc[c];
  }
}

// ---------------- K9: bn3+relu+mean ----------------
__global__ __launch_bounds__(256) void k_out(float* __restrict__ out, const float* __restrict__ ws){
  const float* y3 = ws + OFF_Y3;
  const float* st = ws + OFF_S3;
  int w = blockIdx.x*4 + (threadIdx.x>>6);
  int lane = threadIdx.x & 63;
  int b = w >> 7, c = w & 127;
  const float* p = y3 + (b*C3+c)*LEN3;
  float a = st[c], sh = st[C3+c];
  float s = 0.f;
  for (int i=lane; i<LEN3; i+=64) s += fmaxf(fmaf(a, p[i], sh), 0.f);
  #pragma unroll
  for (int off=32; off; off>>=1) s += __shfl_xor(s,off,64);
  if (lane==0) out[b*C3+c] = s * (1.0f/511.0f);
}

extern "C" void kernel_launch(void* const* d_in, const int* in_sizes, int n_in,
                              void* d_out, int out_size, void* d_ws, size_t ws_size,
                              hipStream_t stream) {
  const float* x   = (const float*)d_in[0];
  const float* c1w = (const float*)d_in[1];
  const float* c1b = (const float*)d_in[2];
  const float* w1  = (const float*)d_in[3];
  const float* b1  = (const float*)d_in[4];
  const float* g1  = (const float*)d_in[5];
  const float* be1 = (const float*)d_in[6];
  const float* w2  = (const float*)d_in[7];
  const float* b2  = (const float*)d_in[8];
  const float* g2  = (const float*)d_in[9];
  const float* be2 = (const float*)d_in[10];
  const float* w3  = (const float*)d_in[11];
  const float* b3  = (const float*)d_in[12];
  const float* g3  = (const float*)d_in[13];
  const float* be3 = (const float*)d_in[14];
  float* ws  = (float*)d_ws;
  float* out = (float*)d_out;

  hipLaunchKernelGGL(k_patch,  dim3((NB*NP)/4), dim3(256), 0, stream, x, ws);
  hipLaunchKernelGGL(k_initc2, dim3((NB*NP+255)/256), dim3(256), 0, stream, c1b, ws);
  hipLaunchKernelGGL(k_gemm,   dim3(32,4,8), dim3(256), 0, stream, c1w, ws);
  hipLaunchKernelGGL(k_conv1,  dim3(8,NB), dim3(256), 0, stream, w1, b1, ws);
  hipLaunchKernelGGL(k_stats,  dim3(NB,C1), dim3(256), 0, stream, ws+OFF_Y1, ws+OFF_PART, C1, LEN1);
  hipLaunchKernelGGL(k_fin,    dim3(C1), dim3(256), 0, stream, ws+OFF_PART, g1, be1, ws+OFF_S1, C1, 1.0/((double)NB*LEN1));
  hipLaunchKernelGGL(k_conv2,  dim3(16,NB), dim3(256), 0, stream, w2, b2, ws);
  hipLaunchKernelGGL(k_stats,  dim3(NB,C2), dim3(256), 0, stream, ws+OFF_Y2, ws+OFF_PART, C2, LEN2);
  hipLaunchKernelGGL(k_fin,    dim3(C2), dim3(256), 0, stream, ws+OFF_PART, g2, be2, ws+OFF_S2, C2, 1.0/((double)NB*LEN2));
  hipLaunchKernelGGL(k_conv3,  dim3(8,2,NB), dim3(256), 0, stream, w3, b3, ws);
  hipLaunchKernelGGL(k_stats,  dim3(NB,C3), dim3(256), 0, stream, ws+OFF_Y3, ws+OFF_PART, C3, LEN3);
  hipLaunchKernelGGL(k_fin,    dim3(C3), dim3(256), 0, stream, ws+OFF_PART, g3, be3, ws+OFF_S3, C3, 1.0/((double)NB*LEN3));
  hipLaunchKernelGGL(k_out,    dim3((NB*C3)/4), dim3(256), 0, stream, out, ws);
}

// Round 3
// 680.893 us; speedup vs baseline: 1.5914x; 1.1943x over previous
//
#include <hip/hip_runtime.h>
#include <math.h>

#define NB 256
#define SEQ 65536
#define NP 2047
#define NPM 2046
#define LEN1 2047
#define LEN2 1023
#define LEN3 511
#define C1 32
#define C2 64
#define C3 128

// workspace offsets (in floats)
#define OFF_X3   0
#define SZ_X3    (NB*3*NP)
#define OFF_DMAX (OFF_X3 + SZ_X3)
#define SZ_DMAX  (NB*NPM)
#define OFF_Y1   (OFF_DMAX + SZ_DMAX)
#define SZ_Y1    (NB*C1*LEN1)
#define OFF_Y2   (OFF_Y1 + SZ_Y1)
#define SZ_Y2    (NB*C2*LEN2)
#define OFF_PART (OFF_Y2 + SZ_Y2)
#define SZ_PART  (C3*NB*2)
#define OFF_S1   (OFF_PART + SZ_PART)
#define OFF_S2   (OFF_S1 + 2*C1)
#define OFF_S3   (OFF_S2 + 2*C2)
#define OFF_Y3   OFF_Y1   // y1 dead after conv2; reuse for y3

// 16-way macro expansion: accumulators MUST be named scalars — acc[16] arrays
// were lowered to scratch twice (R1: VGPR=52/WRITE=70GB, R2: VGPR=12/WRITE=72GB)
#define ACCS16(X) X(0) X(1) X(2) X(3) X(4) X(5) X(6) X(7) \
                  X(8) X(9) X(10) X(11) X(12) X(13) X(14) X(15)

// ---------------- K1: patch mean/std + dmax ----------------
__global__ __launch_bounds__(256) void k_patch(const float* __restrict__ x, float* __restrict__ ws){
  float* x3   = ws + OFF_X3;
  float* dmax = ws + OFF_DMAX;
  int wid  = blockIdx.x*4 + (threadIdx.x>>6);
  int lane = threadIdx.x & 63;
  int b = wid / NP;
  int p = wid - b*NP;
  const float* xb = x + (size_t)b*SEQ + p*32 + lane;
  float v  = xb[0];
  float v2 = (p < NPM) ? xb[32] : v;
  float s = v, q = v*v, d = v2 - v;
  #pragma unroll
  for (int off=32; off; off>>=1){
    s += __shfl_xor(s, off, 64);
    q += __shfl_xor(q, off, 64);
    d  = fmaxf(d, __shfl_xor(d, off, 64));
  }
  if (lane == 0){
    float mean = s * (1.0f/64.0f);
    float var  = (q - s*mean) * (1.0f/63.0f);   // ddof=1
    x3[(b*3+0)*NP + p] = mean;
    x3[(b*3+1)*NP + p] = sqrtf(fmaxf(var, 0.0f));
    if (p < NPM) dmax[b*NPM + p] = d;
  }
}

// ---------------- K0: init x3 channel 2 with conv1_b ----------------
__global__ __launch_bounds__(256) void k_initc2(const float* __restrict__ c1b, float* __restrict__ ws){
  int i = blockIdx.x*256 + threadIdx.x;
  if (i < NB*NP){
    int b = i / NP; int o = i - b*NP;
    ws[OFF_X3 + (b*3+2)*NP + o] = c1b[o];
  }
}

// ---------------- K2: d2[b,o] += sum_k dmax[b,k]*W[o,k]  (split-K sgemm) ----------------
__global__ __launch_bounds__(256) void k_gemm(const float* __restrict__ W, float* __restrict__ ws){
  const float* A = ws + OFF_DMAX;     // [NB][NPM]
  float* x3 = ws + OFF_X3;
  __shared__ float As[16][65];
  __shared__ float Bs[16][65];
  int tid = threadIdx.x;
  int o0 = blockIdx.x * 64;
  int b0 = blockIdx.y * 64;
  int ks = blockIdx.z * 256;
  int ke = min(ks + 256, NPM);
  int tx = tid & 15, ty = tid >> 4;
  float acc[4][4];
  #pragma unroll
  for (int m=0;m<4;m++){
    #pragma unroll
    for (int n=0;n<4;n++) acc[m][n]=0.f;
  }
  int lr = tid >> 2;
  int lc = (tid & 3) * 4;
  for (int kk = ks; kk < ke; kk += 16){
    int rem = ke - kk;
    {
      const float* ap = A + (b0+lr)*NPM + kk + lc;
      #pragma unroll
      for (int j=0;j<4;j++) As[lc+j][lr] = (lc+j < rem) ? ap[j] : 0.f;
    }
    {
      int orow = o0 + lr;
      const float* wp = W + (size_t)orow*NPM + kk + lc;
      #pragma unroll
      for (int j=0;j<4;j++) Bs[lc+j][lr] = (orow < NP && lc+j < rem) ? wp[j] : 0.f;
    }
    __syncthreads();
    #pragma unroll
    for (int k=0;k<16;k++){
      float a[4], w[4];
      #pragma unroll
      for (int m=0;m<4;m++) a[m] = As[k][ty*4+m];
      #pragma unroll
      for (int n=0;n<4;n++) w[n] = Bs[k][tx*4+n];
      #pragma unroll
      for (int m=0;m<4;m++){
        #pragma unroll
        for (int n=0;n<4;n++) acc[m][n] = fmaf(a[m], w[n], acc[m][n]);
      }
    }
    __syncthreads();
  }
  #pragma unroll
  for (int m=0;m<4;m++){
    int b = b0 + ty*4 + m;
    #pragma unroll
    for (int n=0;n<4;n++){
      int o = o0 + tx*4 + n;
      if (o < NP) atomicAdd(&x3[(b*3+2)*NP + o], acc[m][n]);
    }
  }
}

// ---------------- K3: conv1 (3->32, k=5, pad=2) ----------------
__global__ __launch_bounds__(256) void k_conv1(const float* __restrict__ w1, const float* __restrict__ b1, float* __restrict__ ws){
  const float* x3 = ws + OFF_X3;
  float* y1 = ws + OFF_Y1;
  int b = blockIdx.y;
  int l = blockIdx.x*256 + threadIdx.x;
  bool valid = (l < LEN1);
  float xin[3][5];
  #pragma unroll
  for (int i=0;i<3;i++){
    #pragma unroll
    for (int j=0;j<5;j++){
      int t = l + j - 2;
      xin[i][j] = (valid && t >= 0 && t < LEN1) ? x3[(b*3+i)*NP + t] : 0.f;
    }
  }
  #pragma unroll 8
  for (int c=0;c<C1;c++){
    float a = b1[c];
    #pragma unroll
    for (int i=0;i<3;i++){
      #pragma unroll
      for (int j=0;j<5;j++) a = fmaf(w1[(c*3+i)*5+j], xin[i][j], a);
    }
    if (valid) y1[(b*C1+c)*LEN1 + l] = a;
  }
}

// ---------------- stats: per-(b,c) partial sum/sumsq ----------------
__global__ __launch_bounds__(256) void k_stats(const float* __restrict__ y, float* __restrict__ part, int C, int L){
  int b = blockIdx.x, c = blockIdx.y;
  const float* p = y + ((size_t)b*C + c)*L;
  float s=0.f, q=0.f;
  for (int i=threadIdx.x; i<L; i+=256){ float v=p[i]; s+=v; q=fmaf(v,v,q); }
  __shared__ float rs[4], rq[4];
  #pragma unroll
  for (int off=32; off; off>>=1){ s += __shfl_xor(s,off,64); q += __shfl_xor(q,off,64); }
  int wid = threadIdx.x>>6, lane = threadIdx.x&63;
  if (lane==0){ rs[wid]=s; rq[wid]=q; }
  __syncthreads();
  if (threadIdx.x==0){
    part[(c*NB+b)*2+0] = rs[0]+rs[1]+rs[2]+rs[3];
    part[(c*NB+b)*2+1] = rq[0]+rq[1]+rq[2]+rq[3];
  }
}

// ---------------- finalize BN ----------------
__global__ __launch_bounds__(256) void k_fin(const float* __restrict__ part, const float* __restrict__ g,
                                             const float* __restrict__ be, float* __restrict__ stats,
                                             int C, double invN){
  int c = blockIdx.x;
  float s = part[(c*NB+threadIdx.x)*2+0];
  float q = part[(c*NB+threadIdx.x)*2+1];
  #pragma unroll
  for (int off=32; off; off>>=1){ s += __shfl_xor(s,off,64); q += __shfl_xor(q,off,64); }
  __shared__ float rs[4], rq[4];
  int wid = threadIdx.x>>6, lane=threadIdx.x&63;
  if (lane==0){ rs[wid]=s; rq[wid]=q; }
  __syncthreads();
  if (threadIdx.x==0){
    double S = (double)rs[0]+rs[1]+rs[2]+rs[3];
    double Q = (double)rq[0]+rq[1]+rq[2]+rq[3];
    double mean = S*invN;
    double var  = Q*invN - mean*mean;
    double a = (double)g[c] / sqrt(var + 1e-5);
    stats[c]   = (float)a;
    stats[C+c] = (float)((double)be[c] - mean*a);
  }
}

// ---------------- K5: bn1+relu+pool + conv2 (32->64, k=3, pad=1) ----------------
// 4 waves x 16 ch (all 64 out-ch), 64 positions per block. Named-scalar accumulators.
__global__ __launch_bounds__(256) void k_conv2(const float* __restrict__ w2, const float* __restrict__ b2, float* __restrict__ ws){
  const float* y1 = ws + OFF_Y1;
  const float* st = ws + OFF_S1;
  float* y2 = ws + OFF_Y2;
  int b = blockIdx.y;
  int l0 = blockIdx.x*64;
  __shared__ float h[C1][66];
  __shared__ float sa[C1], sb[C1];
  if (threadIdx.x < C1){ sa[threadIdx.x]=st[threadIdx.x]; sb[threadIdx.x]=st[C1+threadIdx.x]; }
  __syncthreads();
  for (int idx=threadIdx.x; idx<C1*66; idx+=256){
    int i = idx/66, mm = idx - i*66;
    int m = mm + l0 - 1;
    float v = 0.f;
    if (m>=0 && m<LEN2){
      const float* p = y1 + (b*C1+i)*LEN1 + 2*m;
      float v0 = fmaf(sa[i], p[0], sb[i]);
      float v1 = fmaf(sa[i], p[1], sb[i]);
      v = fmaxf(fmaxf(v0,v1), 0.f);
    }
    h[i][mm] = v;
  }
  __syncthreads();
  int grp  = __builtin_amdgcn_readfirstlane(threadIdx.x >> 6);  // 0..3, wave-uniform
  int lt   = threadIdx.x & 63;
  int cbase = grp * 16;
  int l = l0 + lt;
  const float* bb = b2 + cbase;                 // wave-uniform
  const float* wb0 = w2 + cbase*C1*3;           // wave-uniform; ch stride = C1*3 = 96
#define DECL2(c) float acc##c = bb[c];
  ACCS16(DECL2)
  for (int i=0;i<C1;i++){
    float hA = h[i][lt], hB = h[i][lt+1], hC = h[i][lt+2];
    const float* wb = wb0 + i*3;
#define FMA2(c) acc##c = fmaf(wb[c*96+0], hA, acc##c); \
                acc##c = fmaf(wb[c*96+1], hB, acc##c); \
                acc##c = fmaf(wb[c*96+2], hC, acc##c);
    ACCS16(FMA2)
  }
  if (l < LEN2){
    float* yp = y2 + ((size_t)b*C2 + cbase)*LEN2 + l;
#define ST2(c) yp[c*LEN2] = acc##c;
    ACCS16(ST2)
  }
}

// ---------------- K7: bn2+relu+pool + conv3 (64->128, k=3, pad=1) ----------------
// grid.y = channel half (64 ch each); 4 waves x 16 ch, 64 positions per block.
__global__ __launch_bounds__(256) void k_conv3(const float* __restrict__ w3, const float* __restrict__ b3, float* __restrict__ ws){
  const float* y2 = ws + OFF_Y2;
  const float* st = ws + OFF_S2;
  float* y3 = ws + OFF_Y3;
  int b = blockIdx.z;
  int zc = blockIdx.y;           // 0 or 1: which 64-channel half
  int l0 = blockIdx.x*64;
  __shared__ float h[C2][66];
  __shared__ float sa[C2], sb[C2];
  if (threadIdx.x < C2){ sa[threadIdx.x]=st[threadIdx.x]; sb[threadIdx.x]=st[C2+threadIdx.x]; }
  __syncthreads();
  for (int idx=threadIdx.x; idx<C2*66; idx+=256){
    int i = idx/66, mm = idx - i*66;
    int m = mm + l0 - 1;
    float v=0.f;
    if (m>=0 && m<LEN3){
      const float* p = y2 + (b*C2+i)*LEN2 + 2*m;
      float v0 = fmaf(sa[i], p[0], sb[i]);
      float v1 = fmaf(sa[i], p[1], sb[i]);
      v = fmaxf(fmaxf(v0,v1), 0.f);
    }
    h[i][mm] = v;
  }
  __syncthreads();
  int grp  = __builtin_amdgcn_readfirstlane(threadIdx.x >> 6);  // 0..3, wave-uniform
  int lt   = threadIdx.x & 63;
  int cbase = zc*64 + grp*16;
  int l = l0 + lt;
  const float* bb = b3 + cbase;                 // wave-uniform
  const float* wb0 = w3 + cbase*C2*3;           // wave-uniform; ch stride = C2*3 = 192
#define DECL3(c) float acc##c = bb[c];
  ACCS16(DECL3)
  for (int i=0;i<C2;i++){
    float hA = h[i][lt], hB = h[i][lt+1], hC = h[i][lt+2];
    const float* wb = wb0 + i*3;
#define FMA3(c) acc##c = fmaf(wb[c*192+0], hA, acc##c); \
                acc##c = fmaf(wb[c*192+1], hB, acc##c); \
                acc##c = fmaf(wb[c*192+2], hC, acc##c);
    ACCS16(FMA3)
  }
  if (l < LEN3){
    float* yp = y3 + ((size_t)b*C3 + cbase)*LEN3 + l;
#define ST3(c) yp[c*LEN3] = acc##c;
    ACCS16(ST3)
  }
}

// ---------------- K9: bn3+relu+mean ----------------
__global__ __launch_bounds__(256) void k_out(float* __restrict__ out, const float* __restrict__ ws){
  const float* y3 = ws + OFF_Y3;
  const float* st = ws + OFF_S3;
  int w = blockIdx.x*4 + (threadIdx.x>>6);
  int lane = threadIdx.x & 63;
  int b = w >> 7, c = w & 127;
  const float* p = y3 + (b*C3+c)*LEN3;
  float a = st[c], sh = st[C3+c];
  float s = 0.f;
  for (int i=lane; i<LEN3; i+=64) s += fmaxf(fmaf(a, p[i], sh), 0.f);
  #pragma unroll
  for (int off=32; off; off>>=1) s += __shfl_xor(s,off,64);
  if (lane==0) out[b*C3+c] = s * (1.0f/511.0f);
}

extern "C" void kernel_launch(void* const* d_in, const int* in_sizes, int n_in,
                              void* d_out, int out_size, void* d_ws, size_t ws_size,
                              hipStream_t stream) {
  const float* x   = (const float*)d_in[0];
  const float* c1w = (const float*)d_in[1];
  const float* c1b = (const float*)d_in[2];
  const float* w1  = (const float*)d_in[3];
  const float* b1  = (const float*)d_in[4];
  const float* g1  = (const float*)d_in[5];
  const float* be1 = (const float*)d_in[6];
  const float* w2  = (const float*)d_in[7];
  const float* b2  = (const float*)d_in[8];
  const float* g2  = (const float*)d_in[9];
  const float* be2 = (const float*)d_in[10];
  const float* w3  = (const float*)d_in[11];
  const float* b3  = (const float*)d_in[12];
  const float* g3  = (const float*)d_in[13];
  const float* be3 = (const float*)d_in[14];
  float* ws  = (float*)d_ws;
  float* out = (float*)d_out;

  hipLaunchKernelGGL(k_patch,  dim3((NB*NP)/4), dim3(256), 0, stream, x, ws);
  hipLaunchKernelGGL(k_initc2, dim3((NB*NP+255)/256), dim3(256), 0, stream, c1b, ws);
  hipLaunchKernelGGL(k_gemm,   dim3(32,4,8), dim3(256), 0, stream, c1w, ws);
  hipLaunchKernelGGL(k_conv1,  dim3(8,NB), dim3(256), 0, stream, w1, b1, ws);
  hipLaunchKernelGGL(k_stats,  dim3(NB,C1), dim3(256), 0, stream, ws+OFF_Y1, ws+OFF_PART, C1, LEN1);
  hipLaunchKernelGGL(k_fin,    dim3(C1), dim3(256), 0, stream, ws+OFF_PART, g1, be1, ws+OFF_S1, C1, 1.0/((double)NB*LEN1));
  hipLaunchKernelGGL(k_conv2,  dim3(16,NB), dim3(256), 0, stream, w2, b2, ws);
  hipLaunchKernelGGL(k_stats,  dim3(NB,C2), dim3(256), 0, stream, ws+OFF_Y2, ws+OFF_PART, C2, LEN2);
  hipLaunchKernelGGL(k_fin,    dim3(C2), dim3(256), 0, stream, ws+OFF_PART, g2, be2, ws+OFF_S2, C2, 1.0/((double)NB*LEN2));
  hipLaunchKernelGGL(k_conv3,  dim3(8,2,NB), dim3(256), 0, stream, w3, b3, ws);
  hipLaunchKernelGGL(k_stats,  dim3(NB,C3), dim3(256), 0, stream, ws+OFF_Y3, ws+OFF_PART, C3, LEN3);
  hipLaunchKernelGGL(k_fin,    dim3(C3), dim3(256), 0, stream, ws+OFF_PART, g3, be3, ws+OFF_S3, C3, 1.0/((double)NB*LEN3));
  hipLaunchKernelGGL(k_out,    dim3((NB*C3)/4), dim3(256), 0, stream, out, ws);
}

// Round 4
// 600.147 us; speedup vs baseline: 1.8055x; 1.1345x over previous
//
#include <hip/hip_runtime.h>
#include <math.h>

#define NB 256
#define SEQ 65536
#define NP 2047
#define NPM 2046
#define LEN1 2047
#define LEN2 1023
#define LEN3 511
#define C1 32
#define C2 64
#define C3 128
#define NPART 2048   // per-channel partial slots for fused stats (NB*8 blocks)

// workspace offsets (in floats)
#define OFF_X3   0
#define SZ_X3    (NB*3*NP)
#define OFF_DMAX (OFF_X3 + SZ_X3)
#define SZ_DMAX  (NB*NPM)
#define OFF_Y1   (OFF_DMAX + SZ_DMAX)
#define SZ_Y1    (NB*C1*LEN1)
#define OFF_Y2   (OFF_Y1 + SZ_Y1)
#define SZ_Y2    (NB*C2*LEN2)
#define OFF_PS   (OFF_Y2 + SZ_Y2)
#define OFF_PQ   (OFF_PS + C3*NPART)
#define OFF_S1   (OFF_PQ + C3*NPART)
#define OFF_S2   (OFF_S1 + 2*C1)
#define OFF_S3   (OFF_S2 + 2*C2)
#define OFF_W2T  (OFF_S3 + 2*C3)
#define OFF_W3T  (OFF_W2T + 96*C2)
#define OFF_Y3   OFF_Y1   // y1 dead after conv2; reuse for y3

// accumulators MUST be named scalars (arrays demoted badly in R1/R2)
#define ACCS16(X) X(0) X(1) X(2) X(3) X(4) X(5) X(6) X(7) \
                  X(8) X(9) X(10) X(11) X(12) X(13) X(14) X(15)
#define ACCS32(X) ACCS16(X) X(16) X(17) X(18) X(19) X(20) X(21) X(22) X(23) \
                  X(24) X(25) X(26) X(27) X(28) X(29) X(30) X(31)

#define RED6(v) v += __shfl_xor(v,32,64); v += __shfl_xor(v,16,64); \
                v += __shfl_xor(v, 8,64); v += __shfl_xor(v, 4,64); \
                v += __shfl_xor(v, 2,64); v += __shfl_xor(v, 1,64);

// ---------------- K1: patch mean/std + dmax ----------------
__global__ __launch_bounds__(256) void k_patch(const float* __restrict__ x, float* __restrict__ ws){
  float* x3   = ws + OFF_X3;
  float* dmax = ws + OFF_DMAX;
  int wid  = blockIdx.x*4 + (threadIdx.x>>6);
  int lane = threadIdx.x & 63;
  int b = wid / NP;
  int p = wid - b*NP;
  const float* xb = x + (size_t)b*SEQ + p*32 + lane;
  float v  = xb[0];
  float v2 = (p < NPM) ? xb[32] : v;
  float s = v, q = v*v, d = v2 - v;
  #pragma unroll
  for (int off=32; off; off>>=1){
    s += __shfl_xor(s, off, 64);
    q += __shfl_xor(q, off, 64);
    d  = fmaxf(d, __shfl_xor(d, off, 64));
  }
  if (lane == 0){
    float mean = s * (1.0f/64.0f);
    float var  = (q - s*mean) * (1.0f/63.0f);   // ddof=1
    x3[(b*3+0)*NP + p] = mean;
    x3[(b*3+1)*NP + p] = sqrtf(fmaxf(var, 0.0f));
    if (p < NPM) dmax[b*NPM + p] = d;
  }
}

// ---------------- K0: init x3 channel 2 with conv1_b ----------------
__global__ __launch_bounds__(256) void k_initc2(const float* __restrict__ c1b, float* __restrict__ ws){
  int i = blockIdx.x*256 + threadIdx.x;
  if (i < NB*NP){
    int b = i / NP; int o = i - b*NP;
    ws[OFF_X3 + (b*3+2)*NP + o] = c1b[o];
  }
}

// ---------------- K_wt: transpose weights to [i*3+tap][c] ----------------
__global__ __launch_bounds__(256) void k_wt(const float* __restrict__ w2, const float* __restrict__ w3, float* __restrict__ ws){
  float* w2t = ws + OFF_W2T;
  float* w3t = ws + OFF_W3T;
  int t = blockIdx.x*256 + threadIdx.x;
  if (t < 96*C2){
    int r = t / C2, c = t - r*C2;
    int i = r/3, tap = r - i*3;
    w2t[t] = w2[(c*C1+i)*3 + tap];
  }
  if (t < 192*C3){
    int r = t / C3, c = t - r*C3;
    int i = r/3, tap = r - i*3;
    w3t[t] = w3[(c*C2+i)*3 + tap];
  }
}

// ---------------- K2: d2[b,o] += sum_k dmax[b,k]*W[o,k]  (split-K sgemm) ----------------
__global__ __launch_bounds__(256) void k_gemm(const float* __restrict__ W, float* __restrict__ ws){
  const float* A = ws + OFF_DMAX;     // [NB][NPM]
  float* x3 = ws + OFF_X3;
  __shared__ float As[16][65];
  __shared__ float Bs[16][65];
  int tid = threadIdx.x;
  int o0 = blockIdx.x * 64;
  int b0 = blockIdx.y * 64;
  int ks = blockIdx.z * 256;
  int ke = min(ks + 256, NPM);
  int tx = tid & 15, ty = tid >> 4;
  float acc[4][4];
  #pragma unroll
  for (int m=0;m<4;m++){
    #pragma unroll
    for (int n=0;n<4;n++) acc[m][n]=0.f;
  }
  int lr = tid >> 2;
  int lc = (tid & 3) * 4;
  for (int kk = ks; kk < ke; kk += 16){
    int rem = ke - kk;
    {
      const float* ap = A + (b0+lr)*NPM + kk + lc;
      #pragma unroll
      for (int j=0;j<4;j++) As[lc+j][lr] = (lc+j < rem) ? ap[j] : 0.f;
    }
    {
      int orow = o0 + lr;
      const float* wp = W + (size_t)orow*NPM + kk + lc;
      #pragma unroll
      for (int j=0;j<4;j++) Bs[lc+j][lr] = (orow < NP && lc+j < rem) ? wp[j] : 0.f;
    }
    __syncthreads();
    #pragma unroll
    for (int k=0;k<16;k++){
      float a[4], w[4];
      #pragma unroll
      for (int m=0;m<4;m++) a[m] = As[k][ty*4+m];
      #pragma unroll
      for (int n=0;n<4;n++) w[n] = Bs[k][tx*4+n];
      #pragma unroll
      for (int m=0;m<4;m++){
        #pragma unroll
        for (int n=0;n<4;n++) acc[m][n] = fmaf(a[m], w[n], acc[m][n]);
      }
    }
    __syncthreads();
  }
  #pragma unroll
  for (int m=0;m<4;m++){
    int b = b0 + ty*4 + m;
    #pragma unroll
    for (int n=0;n<4;n++){
      int o = o0 + tx*4 + n;
      if (o < NP) atomicAdd(&x3[(b*3+2)*NP + o], acc[m][n]);
    }
  }
}

// ---------------- K3: conv1 (3->32, k=5, pad=2) ----------------
__global__ __launch_bounds__(256) void k_conv1(const float* __restrict__ w1, const float* __restrict__ b1, float* __restrict__ ws){
  const float* x3 = ws + OFF_X3;
  float* y1 = ws + OFF_Y1;
  int b = blockIdx.y;
  int l = blockIdx.x*256 + threadIdx.x;
  bool valid = (l < LEN1);
  float xin[3][5];
  #pragma unroll
  for (int i=0;i<3;i++){
    #pragma unroll
    for (int j=0;j<5;j++){
      int t = l + j - 2;
      xin[i][j] = (valid && t >= 0 && t < LEN1) ? x3[(b*3+i)*NP + t] : 0.f;
    }
  }
  #pragma unroll 8
  for (int c=0;c<C1;c++){
    float a = b1[c];
    #pragma unroll
    for (int i=0;i<3;i++){
      #pragma unroll
      for (int j=0;j<5;j++) a = fmaf(w1[(c*3+i)*5+j], xin[i][j], a);
    }
    if (valid) y1[(b*C1+c)*LEN1 + l] = a;
  }
}

// ---------------- stats (layer1 only): per-(b,c) sum/sumsq ----------------
__global__ __launch_bounds__(256) void k_stats(const float* __restrict__ y, float* __restrict__ ps,
                                               float* __restrict__ pq, int C, int L, int npart){
  int b = blockIdx.x, c = blockIdx.y;
  const float* p = y + ((size_t)b*C + c)*L;
  float s=0.f, q=0.f;
  for (int i=threadIdx.x; i<L; i+=256){ float v=p[i]; s+=v; q=fmaf(v,v,q); }
  __shared__ float rs[4], rq[4];
  RED6(s) RED6(q)
  int wid = threadIdx.x>>6, lane = threadIdx.x&63;
  if (lane==0){ rs[wid]=s; rq[wid]=q; }
  __syncthreads();
  if (threadIdx.x==0){
    ps[c*npart + b] = rs[0]+rs[1]+rs[2]+rs[3];
    pq[c*npart + b] = rq[0]+rq[1]+rq[2]+rq[3];
  }
}

// ---------------- finalize BN from partials ----------------
__global__ __launch_bounds__(256) void k_fin(const float* __restrict__ ps, const float* __restrict__ pq,
                                             const float* __restrict__ g, const float* __restrict__ be,
                                             float* __restrict__ stats, int C, int npart, double invN){
  int c = blockIdx.x;
  double s=0.0, q=0.0;
  for (int j=threadIdx.x; j<npart; j+=256){ s += (double)ps[c*npart+j]; q += (double)pq[c*npart+j]; }
  #pragma unroll
  for (int off=32; off; off>>=1){ s += __shfl_xor(s,off,64); q += __shfl_xor(q,off,64); }
  __shared__ double rs[4], rq[4];
  int wid = threadIdx.x>>6, lane=threadIdx.x&63;
  if (lane==0){ rs[wid]=s; rq[wid]=q; }
  __syncthreads();
  if (threadIdx.x==0){
    double S = rs[0]+rs[1]+rs[2]+rs[3];
    double Q = rq[0]+rq[1]+rq[2]+rq[3];
    double mean = S*invN;
    double var  = Q*invN - mean*mean;
    double a = (double)g[c] / sqrt(var + 1e-5);
    stats[c]   = (float)a;
    stats[C+c] = (float)((double)be[c] - mean*a);
  }
}

// ---------------- K5: bn1+relu+pool + conv2 (32->64, k=3, pad=1) + fused stats ----------------
// block = 128 positions x 64 ch; 4 waves x 16 ch; 2 positions/thread (32 accs).
__global__ __launch_bounds__(256) void k_conv2(const float* __restrict__ b2, float* __restrict__ ws){
  const float* y1  = ws + OFF_Y1;
  const float* st  = ws + OFF_S1;
  const float* w2t = ws + OFF_W2T;
  float* y2 = ws + OFF_Y2;
  float* ps = ws + OFF_PS;
  float* pq = ws + OFF_PQ;
  int b = blockIdx.y;
  int blk = blockIdx.x;
  int l0 = blk*128;
  __shared__ float h[C1][130];
  __shared__ float sa[C1], sb[C1];
  if (threadIdx.x < C1){ sa[threadIdx.x]=st[threadIdx.x]; sb[threadIdx.x]=st[C1+threadIdx.x]; }
  __syncthreads();
  for (int idx=threadIdx.x; idx<C1*130; idx+=256){
    int i = idx/130, mm = idx - i*130;
    int m = mm + l0 - 1;
    float v = 0.f;
    if (m>=0 && m<LEN2){
      const float* p = y1 + (b*C1+i)*LEN1 + 2*m;
      float v0 = fmaf(sa[i], p[0], sb[i]);
      float v1 = fmaf(sa[i], p[1], sb[i]);
      v = fmaxf(fmaxf(v0,v1), 0.f);
    }
    h[i][mm] = v;
  }
  __syncthreads();
  int grp  = __builtin_amdgcn_readfirstlane(threadIdx.x >> 6);  // 0..3, wave-uniform
  int lt   = threadIdx.x & 63;
  int cb   = grp * 16;
  const float* bb = b2 + cb;                    // wave-uniform
#define DECL2(c) float accA##c = bb[c]; float accB##c = accA##c;
  ACCS16(DECL2)
  for (int i=0;i<C1;i++){
    const float* wr = w2t + (i*3)*C2 + cb;      // wave-uniform; taps at +0, +C2, +2*C2
    float a0 = h[i][lt],    a1 = h[i][lt+1],  a2 = h[i][lt+2];
    float p0 = h[i][lt+64], p1 = h[i][lt+65], p2 = h[i][lt+66];
#define FMA2(c) { float w0_=wr[c], w1_=wr[C2+c], w2_=wr[2*C2+c]; \
                  accA##c = fmaf(w0_, a0, accA##c); accA##c = fmaf(w1_, a1, accA##c); accA##c = fmaf(w2_, a2, accA##c); \
                  accB##c = fmaf(w0_, p0, accB##c); accB##c = fmaf(w1_, p1, accB##c); accB##c = fmaf(w2_, p2, accB##c); }
    ACCS16(FMA2)
  }
  int lA = l0 + lt, lB = lA + 64;
  bool vB = (lB < LEN2);
  float* yp = y2 + ((size_t)b*C2 + cb)*LEN2 + lA;
#define ST2(c) { yp[c*LEN2] = accA##c; if (vB) yp[c*LEN2+64] = accB##c; }
  ACCS16(ST2)
  int pidx = b*8 + blk;
#define RD2(c) { float vA_=accA##c, vb_=vB?accB##c:0.f; \
                 float s_=vA_+vb_; float q_=fmaf(vA_,vA_, vb_*vb_); \
                 RED6(s_) RED6(q_) \
                 if (lt==0){ ps[(cb+c)*NPART + pidx]=s_; pq[(cb+c)*NPART + pidx]=q_; } }
  ACCS16(RD2)
}

// ---------------- K7: bn2+relu+pool + conv3 (64->128, k=3, pad=1) + fused stats ----------------
// block = 64 positions x all 128 ch; 4 waves x 32 ch (32 accs).
__global__ __launch_bounds__(256) void k_conv3(const float* __restrict__ b3, float* __restrict__ ws){
  const float* y2  = ws + OFF_Y2;
  const float* st  = ws + OFF_S2;
  const float* w3t = ws + OFF_W3T;
  float* y3 = ws + OFF_Y3;
  float* ps = ws + OFF_PS;
  float* pq = ws + OFF_PQ;
  int b = blockIdx.y;
  int blk = blockIdx.x;
  int l0 = blk*64;
  __shared__ float h[C2][66];
  __shared__ float sa[C2], sb[C2];
  if (threadIdx.x < C2){ sa[threadIdx.x]=st[threadIdx.x]; sb[threadIdx.x]=st[C2+threadIdx.x]; }
  __syncthreads();
  for (int idx=threadIdx.x; idx<C2*66; idx+=256){
    int i = idx/66, mm = idx - i*66;
    int m = mm + l0 - 1;
    float v=0.f;
    if (m>=0 && m<LEN3){
      const float* p = y2 + (b*C2+i)*LEN2 + 2*m;
      float v0 = fmaf(sa[i], p[0], sb[i]);
      float v1 = fmaf(sa[i], p[1], sb[i]);
      v = fmaxf(fmaxf(v0,v1), 0.f);
    }
    h[i][mm] = v;
  }
  __syncthreads();
  int grp  = __builtin_amdgcn_readfirstlane(threadIdx.x >> 6);  // 0..3, wave-uniform
  int lt   = threadIdx.x & 63;
  int cb   = grp * 32;
  const float* bb = b3 + cb;                    // wave-uniform
#define DECL3(c) float acc##c = bb[c];
  ACCS32(DECL3)
  for (int i=0;i<C2;i++){
    const float* wr = w3t + (i*3)*C3 + cb;      // wave-uniform; taps at +0, +C3, +2*C3
    float a0 = h[i][lt], a1 = h[i][lt+1], a2 = h[i][lt+2];
#define FMA3(c) acc##c = fmaf(wr[c],      a0, acc##c); \
                acc##c = fmaf(wr[C3+c],   a1, acc##c); \
                acc##c = fmaf(wr[2*C3+c], a2, acc##c);
    ACCS32(FMA3)
  }
  int l = l0 + lt;
  bool vL = (l < LEN3);
  float* yp = y3 + ((size_t)b*C3 + cb)*LEN3 + l;
#define ST3(c) if (vL) yp[c*LEN3] = acc##c;
  ACCS32(ST3)
  int pidx = b*8 + blk;
#define RD3(c) { float v_= vL ? acc##c : 0.f; \
                 float s_=v_; float q_=v_*v_; \
                 RED6(s_) RED6(q_) \
                 if (lt==0){ ps[(cb+c)*NPART + pidx]=s_; pq[(cb+c)*NPART + pidx]=q_; } }
  ACCS32(RD3)
}

// ---------------- K9: bn3+relu+mean ----------------
__global__ __launch_bounds__(256) void k_out(float* __restrict__ out, const float* __restrict__ ws){
  const float* y3 = ws + OFF_Y3;
  const float* st = ws + OFF_S3;
  int w = blockIdx.x*4 + (threadIdx.x>>6);
  int lane = threadIdx.x & 63;
  int b = w >> 7, c = w & 127;
  const float* p = y3 + (b*C3+c)*LEN3;
  float a = st[c], sh = st[C3+c];
  float s = 0.f;
  for (int i=lane; i<LEN3; i+=64) s += fmaxf(fmaf(a, p[i], sh), 0.f);
  #pragma unroll
  for (int off=32; off; off>>=1) s += __shfl_xor(s,off,64);
  if (lane==0) out[b*C3+c] = s * (1.0f/511.0f);
}

extern "C" void kernel_launch(void* const* d_in, const int* in_sizes, int n_in,
                              void* d_out, int out_size, void* d_ws, size_t ws_size,
                              hipStream_t stream) {
  const float* x   = (const float*)d_in[0];
  const float* c1w = (const float*)d_in[1];
  const float* c1b = (const float*)d_in[2];
  const float* w1  = (const float*)d_in[3];
  const float* b1  = (const float*)d_in[4];
  const float* g1  = (const float*)d_in[5];
  const float* be1 = (const float*)d_in[6];
  const float* w2  = (const float*)d_in[7];
  const float* b2  = (const float*)d_in[8];
  const float* g2  = (const float*)d_in[9];
  const float* be2 = (const float*)d_in[10];
  const float* w3  = (const float*)d_in[11];
  const float* b3  = (const float*)d_in[12];
  const float* g3  = (const float*)d_in[13];
  const float* be3 = (const float*)d_in[14];
  float* ws  = (float*)d_ws;
  float* out = (float*)d_out;

  hipLaunchKernelGGL(k_patch,  dim3((NB*NP)/4), dim3(256), 0, stream, x, ws);
  hipLaunchKernelGGL(k_initc2, dim3((NB*NP+255)/256), dim3(256), 0, stream, c1b, ws);
  hipLaunchKernelGGL(k_wt,     dim3((192*C3+255)/256), dim3(256), 0, stream, w2, w3, ws);
  hipLaunchKernelGGL(k_gemm,   dim3(32,4,8), dim3(256), 0, stream, c1w, ws);
  hipLaunchKernelGGL(k_conv1,  dim3(8,NB), dim3(256), 0, stream, w1, b1, ws);
  hipLaunchKernelGGL(k_stats,  dim3(NB,C1), dim3(256), 0, stream, ws+OFF_Y1, ws+OFF_PS, ws+OFF_PQ, C1, LEN1, NB);
  hipLaunchKernelGGL(k_fin,    dim3(C1), dim3(256), 0, stream, ws+OFF_PS, ws+OFF_PQ, g1, be1, ws+OFF_S1, C1, NB, 1.0/((double)NB*LEN1));
  hipLaunchKernelGGL(k_conv2,  dim3(8,NB), dim3(256), 0, stream, b2, ws);
  hipLaunchKernelGGL(k_fin,    dim3(C2), dim3(256), 0, stream, ws+OFF_PS, ws+OFF_PQ, g2, be2, ws+OFF_S2, C2, NPART, 1.0/((double)NB*LEN2));
  hipLaunchKernelGGL(k_conv3,  dim3(8,NB), dim3(256), 0, stream, b3, ws);
  hipLaunchKernelGGL(k_fin,    dim3(C3), dim3(256), 0, stream, ws+OFF_PS, ws+OFF_PQ, g3, be3, ws+OFF_S3, C3, NPART, 1.0/((double)NB*LEN3));
  hipLaunchKernelGGL(k_out,    dim3((NB*C3)/4), dim3(256), 0, stream, out, ws);
}

// Round 5
// 501.558 us; speedup vs baseline: 2.1604x; 1.1966x over previous
//
#include <hip/hip_runtime.h>
#include <math.h>

#define NB 256
#define SEQ 65536
#define NP 2047
#define NPM 2046
#define LEN1 2047
#define LEN2 1023
#define LEN3 511
#define C1 32
#define C2 64
#define C3 128
#define NPART 2048   // per-channel partial slots for fused stats (NB*8 blocks)

// workspace offsets (in floats)
#define OFF_X3   0
#define SZ_X3    (NB*3*NP)
#define OFF_DMAX (OFF_X3 + SZ_X3)
#define SZ_DMAX  (NB*NPM)
#define OFF_Y1   (OFF_DMAX + SZ_DMAX)
#define SZ_Y1    (NB*C1*LEN1)
#define OFF_Y2   (OFF_Y1 + SZ_Y1)
#define SZ_Y2    (NB*C2*LEN2)
#define OFF_PS   (OFF_Y2 + SZ_Y2)
#define OFF_PQ   (OFF_PS + C3*NPART)
#define OFF_S1   (OFF_PQ + C3*NPART)
#define OFF_S2   (OFF_S1 + 2*C1)
#define OFF_S3   (OFF_S2 + 2*C2)
#define OFF_W2T  (OFF_S3 + 2*C3)
#define OFF_W3T  (OFF_W2T + 96*C2)
#define OFF_Y3   OFF_Y1   // y1 dead after conv2; reuse for y3

// accumulators MUST be named scalars (arrays demoted badly in R1/R2)
#define ACCS16(X) X(0) X(1) X(2) X(3) X(4) X(5) X(6) X(7) \
                  X(8) X(9) X(10) X(11) X(12) X(13) X(14) X(15)
#define ACCS32(X) ACCS16(X) X(16) X(17) X(18) X(19) X(20) X(21) X(22) X(23) \
                  X(24) X(25) X(26) X(27) X(28) X(29) X(30) X(31)

#define RED6(v) v += __shfl_xor(v,32,64); v += __shfl_xor(v,16,64); \
                v += __shfl_xor(v, 8,64); v += __shfl_xor(v, 4,64); \
                v += __shfl_xor(v, 2,64); v += __shfl_xor(v, 1,64);

// ---------------- K1: patch mean/std + dmax via 32-block partials ----------------
// Patch p = 32-blocks (p, p+1). d[t]=x[t+32]-x[t]: partner is 8 lanes ahead in a
// float4-per-lane segment. One 3-level segmented reduce per 256 elements.
__global__ __launch_bounds__(256) void k_patch(const float* __restrict__ x, float* __restrict__ ws){
  float* x3   = ws + OFF_X3;
  float* dmax = ws + OFF_DMAX;
  int b = blockIdx.y;
  int chunk = blockIdx.x;              // 0..31, 2048 floats each
  const float* xr = x + (size_t)b*SEQ + chunk*2048;
  __shared__ float Ss[65], Qs[65], Dm[65];
  int w = threadIdx.x >> 6;
  int l = threadIdx.x & 63;
  #pragma unroll
  for (int i=0;i<2;i++){
    int seg = w*2 + i;                 // 0..7
    int off = seg*256;
    float4 A = *(const float4*)(xr + off + l*4);
    float4 Bh = make_float4(0.f,0.f,0.f,0.f);
    if (l >= 56){
      int g = chunk*2048 + off + 256 + (l-56)*4;
      if (g + 3 < SEQ) Bh = *(const float4*)(xr + off + 256 + (l-56)*4);
    }
    int src = (l+8) & 63;
    float p0 = __shfl(A.x, src, 64), p1 = __shfl(A.y, src, 64),
          p2 = __shfl(A.z, src, 64), p3 = __shfl(A.w, src, 64);
    if (l >= 56){ p0=Bh.x; p1=Bh.y; p2=Bh.z; p3=Bh.w; }
    float s = (A.x+A.y)+(A.z+A.w);
    float q = fmaf(A.x,A.x, fmaf(A.y,A.y, fmaf(A.z,A.z, A.w*A.w)));
    float d = fmaxf(fmaxf(p0-A.x, p1-A.y), fmaxf(p2-A.z, p3-A.w));
    #pragma unroll
    for (int o=1;o<8;o<<=1){
      s += __shfl_xor(s,o,64);
      q += __shfl_xor(q,o,64);
      d  = fmaxf(d, __shfl_xor(d,o,64));
    }
    if ((l&7)==0){ int m = seg*8 + (l>>3); Ss[m]=s; Qs[m]=q; Dm[m]=d; }
  }
  if (w==0){                            // halo: 32-block index 64 of this chunk
    float s=0.f,q=0.f,d=-1e30f;
    if (l < 8){
      int g = chunk*2048 + 2048 + l*4;
      if (g+3 < SEQ){
        float4 A = *(const float4*)(xr + 2048 + l*4);
        float4 P = make_float4(0.f,0.f,0.f,0.f);
        if (g+35 < SEQ) P = *(const float4*)(xr + 2048 + 32 + l*4);
        s = (A.x+A.y)+(A.z+A.w);
        q = fmaf(A.x,A.x, fmaf(A.y,A.y, fmaf(A.z,A.z, A.w*A.w)));
        d = fmaxf(fmaxf(P.x-A.x, P.y-A.y), fmaxf(P.z-A.z, P.w-A.w));
      }
    }
    #pragma unroll
    for (int o=1;o<8;o<<=1){
      s += __shfl_xor(s,o,64);
      q += __shfl_xor(q,o,64);
      d  = fmaxf(d, __shfl_xor(d,o,64));
    }
    if (l==0){ Ss[64]=s; Qs[64]=q; Dm[64]=d; }
  }
  __syncthreads();
  if (threadIdx.x < 64){
    int j = threadIdx.x;
    int p = chunk*64 + j;
    if (p < NP){
      float S = Ss[j]+Ss[j+1];
      float Q = Qs[j]+Qs[j+1];
      float mean = S*(1.0f/64.0f);
      float var  = (Q - S*mean)*(1.0f/63.0f);   // ddof=1
      x3[(b*3+0)*NP + p] = mean;
      x3[(b*3+1)*NP + p] = sqrtf(fmaxf(var,0.0f));
      if (p < NPM) dmax[b*NPM + p] = fmaxf(Dm[j], Dm[j+1]);
    }
  }
}

// ---------------- K0: init x3 channel 2 with conv1_b ----------------
__global__ __launch_bounds__(256) void k_initc2(const float* __restrict__ c1b, float* __restrict__ ws){
  int i = blockIdx.x*256 + threadIdx.x;
  if (i < NB*NP){
    int b = i / NP; int o = i - b*NP;
    ws[OFF_X3 + (b*3+2)*NP + o] = c1b[o];
  }
}

// ---------------- K_wt: transpose weights to [i*3+tap][c] ----------------
__global__ __launch_bounds__(256) void k_wt(const float* __restrict__ w2, const float* __restrict__ w3, float* __restrict__ ws){
  float* w2t = ws + OFF_W2T;
  float* w3t = ws + OFF_W3T;
  int t = blockIdx.x*256 + threadIdx.x;
  if (t < 96*C2){
    int r = t / C2, c = t - r*C2;
    int i = r/3, tap = r - i*3;
    w2t[t] = w2[(c*C1+i)*3 + tap];
  }
  if (t < 192*C3){
    int r = t / C3, c = t - r*C3;
    int i = r/3, tap = r - i*3;
    w3t[t] = w3[(c*C2+i)*3 + tap];
  }
}

// ---------------- K2: d2[b,o] += sum_k dmax[b,k]*W[o,k]  (split-K sgemm) ----------------
__global__ __launch_bounds__(256) void k_gemm(const float* __restrict__ W, float* __restrict__ ws){
  const float* A = ws + OFF_DMAX;     // [NB][NPM]
  float* x3 = ws + OFF_X3;
  __shared__ float As[16][65];
  __shared__ float Bs[16][65];
  int tid = threadIdx.x;
  int o0 = blockIdx.x * 64;
  int b0 = blockIdx.y * 64;
  int ks = blockIdx.z * 256;
  int ke = min(ks + 256, NPM);
  int tx = tid & 15, ty = tid >> 4;
  float acc[4][4];
  #pragma unroll
  for (int m=0;m<4;m++){
    #pragma unroll
    for (int n=0;n<4;n++) acc[m][n]=0.f;
  }
  int lr = tid >> 2;
  int lc = (tid & 3) * 4;
  for (int kk = ks; kk < ke; kk += 16){
    int rem = ke - kk;
    {
      const float* ap = A + (b0+lr)*NPM + kk + lc;
      #pragma unroll
      for (int j=0;j<4;j++) As[lc+j][lr] = (lc+j < rem) ? ap[j] : 0.f;
    }
    {
      int orow = o0 + lr;
      const float* wp = W + (size_t)orow*NPM + kk + lc;
      #pragma unroll
      for (int j=0;j<4;j++) Bs[lc+j][lr] = (orow < NP && lc+j < rem) ? wp[j] : 0.f;
    }
    __syncthreads();
    #pragma unroll
    for (int k=0;k<16;k++){
      float a[4], w[4];
      #pragma unroll
      for (int m=0;m<4;m++) a[m] = As[k][ty*4+m];
      #pragma unroll
      for (int n=0;n<4;n++) w[n] = Bs[k][tx*4+n];
      #pragma unroll
      for (int m=0;m<4;m++){
        #pragma unroll
        for (int n=0;n<4;n++) acc[m][n] = fmaf(a[m], w[n], acc[m][n]);
      }
    }
    __syncthreads();
  }
  #pragma unroll
  for (int m=0;m<4;m++){
    int b = b0 + ty*4 + m;
    #pragma unroll
    for (int n=0;n<4;n++){
      int o = o0 + tx*4 + n;
      if (o < NP) atomicAdd(&x3[(b*3+2)*NP + o], acc[m][n]);
    }
  }
}

// ---------------- K3: conv1 (3->32, k=5, pad=2) ----------------
__global__ __launch_bounds__(256) void k_conv1(const float* __restrict__ w1, const float* __restrict__ b1, float* __restrict__ ws){
  const float* x3 = ws + OFF_X3;
  float* y1 = ws + OFF_Y1;
  int b = blockIdx.y;
  int l = blockIdx.x*256 + threadIdx.x;
  bool valid = (l < LEN1);
  float xin[3][5];
  #pragma unroll
  for (int i=0;i<3;i++){
    #pragma unroll
    for (int j=0;j<5;j++){
      int t = l + j - 2;
      xin[i][j] = (valid && t >= 0 && t < LEN1) ? x3[(b*3+i)*NP + t] : 0.f;
    }
  }
  #pragma unroll 8
  for (int c=0;c<C1;c++){
    float a = b1[c];
    #pragma unroll
    for (int i=0;i<3;i++){
      #pragma unroll
      for (int j=0;j<5;j++) a = fmaf(w1[(c*3+i)*5+j], xin[i][j], a);
    }
    if (valid) y1[(b*C1+c)*LEN1 + l] = a;
  }
}

// ---------------- stats (layer1 only): per-(b,c) sum/sumsq ----------------
__global__ __launch_bounds__(256) void k_stats(const float* __restrict__ y, float* __restrict__ ps,
                                               float* __restrict__ pq, int C, int L, int npart){
  int b = blockIdx.x, c = blockIdx.y;
  const float* p = y + ((size_t)b*C + c)*L;
  float s=0.f, q=0.f;
  for (int i=threadIdx.x; i<L; i+=256){ float v=p[i]; s+=v; q=fmaf(v,v,q); }
  __shared__ float rs[4], rq[4];
  RED6(s) RED6(q)
  int wid = threadIdx.x>>6, lane = threadIdx.x&63;
  if (lane==0){ rs[wid]=s; rq[wid]=q; }
  __syncthreads();
  if (threadIdx.x==0){
    ps[c*npart + b] = rs[0]+rs[1]+rs[2]+rs[3];
    pq[c*npart + b] = rq[0]+rq[1]+rq[2]+rq[3];
  }
}

// ---------------- finalize BN from partials ----------------
__global__ __launch_bounds__(256) void k_fin(const float* __restrict__ ps, const float* __restrict__ pq,
                                             const float* __restrict__ g, const float* __restrict__ be,
                                             float* __restrict__ stats, int C, int npart, double invN){
  int c = blockIdx.x;
  double s=0.0, q=0.0;
  for (int j=threadIdx.x; j<npart; j+=256){ s += (double)ps[c*npart+j]; q += (double)pq[c*npart+j]; }
  #pragma unroll
  for (int off=32; off; off>>=1){ s += __shfl_xor(s,off,64); q += __shfl_xor(q,off,64); }
  __shared__ double rs[4], rq[4];
  int wid = threadIdx.x>>6, lane=threadIdx.x&63;
  if (lane==0){ rs[wid]=s; rq[wid]=q; }
  __syncthreads();
  if (threadIdx.x==0){
    double S = rs[0]+rs[1]+rs[2]+rs[3];
    double Q = rq[0]+rq[1]+rq[2]+rq[3];
    double mean = S*invN;
    double var  = Q*invN - mean*mean;
    double a = (double)g[c] / sqrt(var + 1e-5);
    stats[c]   = (float)a;
    stats[C+c] = (float)((double)be[c] - mean*a);
  }
}

// ---------------- K5: bn1+relu+pool + conv2 (32->64, k=3, pad=1) + fused stats ----------------
// block = 128 positions x 64 ch; 4 waves x 16 ch; 2 positions/thread (32 accs).
__global__ __launch_bounds__(256) void k_conv2(const float* __restrict__ b2, float* __restrict__ ws){
  const float* y1  = ws + OFF_Y1;
  const float* st  = ws + OFF_S1;
  const float* w2t = ws + OFF_W2T;
  float* y2 = ws + OFF_Y2;
  float* ps = ws + OFF_PS;
  float* pq = ws + OFF_PQ;
  int b = blockIdx.y;
  int blk = blockIdx.x;
  int l0 = blk*128;
  __shared__ float h[C1][130];
  __shared__ float sa[C1], sb[C1];
  if (threadIdx.x < C1){ sa[threadIdx.x]=st[threadIdx.x]; sb[threadIdx.x]=st[C1+threadIdx.x]; }
  __syncthreads();
  for (int idx=threadIdx.x; idx<C1*130; idx+=256){
    int i = idx/130, mm = idx - i*130;
    int m = mm + l0 - 1;
    float v = 0.f;
    if (m>=0 && m<LEN2){
      const float* p = y1 + (b*C1+i)*LEN1 + 2*m;
      float v0 = fmaf(sa[i], p[0], sb[i]);
      float v1 = fmaf(sa[i], p[1], sb[i]);
      v = fmaxf(fmaxf(v0,v1), 0.f);
    }
    h[i][mm] = v;
  }
  __syncthreads();
  int grp  = __builtin_amdgcn_readfirstlane(threadIdx.x >> 6);  // 0..3, wave-uniform
  int lt   = threadIdx.x & 63;
  int cb   = grp * 16;
  const float* bb = b2 + cb;                    // wave-uniform
#define DECL2(c) float accA##c = bb[c]; float accB##c = accA##c;
  ACCS16(DECL2)
  for (int i=0;i<C1;i++){
    const float* wr = w2t + (i*3)*C2 + cb;      // wave-uniform; taps at +0, +C2, +2*C2
    float a0 = h[i][lt],    a1 = h[i][lt+1],  a2 = h[i][lt+2];
    float p0 = h[i][lt+64], p1 = h[i][lt+65], p2 = h[i][lt+66];
#define FMA2(c) { float w0_=wr[c], w1_=wr[C2+c], w2_=wr[2*C2+c]; \
                  accA##c = fmaf(w0_, a0, accA##c); accA##c = fmaf(w1_, a1, accA##c); accA##c = fmaf(w2_, a2, accA##c); \
                  accB##c = fmaf(w0_, p0, accB##c); accB##c = fmaf(w1_, p1, accB##c); accB##c = fmaf(w2_, p2, accB##c); }
    ACCS16(FMA2)
  }
  int lA = l0 + lt, lB = lA + 64;
  bool vB = (lB < LEN2);
  float* yp = y2 + ((size_t)b*C2 + cb)*LEN2 + lA;
#define ST2(c) { yp[c*LEN2] = accA##c; if (vB) yp[c*LEN2+64] = accB##c; }
  ACCS16(ST2)
  int pidx = b*8 + blk;
#define RD2(c) { float vA_=accA##c, vb_=vB?accB##c:0.f; \
                 float s_=vA_+vb_; float q_=fmaf(vA_,vA_, vb_*vb_); \
                 RED6(s_) RED6(q_) \
                 if (lt==0){ ps[(cb+c)*NPART + pidx]=s_; pq[(cb+c)*NPART + pidx]=q_; } }
  ACCS16(RD2)
}

// ---------------- K7: bn2+relu+pool + conv3 (64->128, k=3, pad=1) + fused stats ----------------
// block = 64 positions x all 128 ch; 4 waves x 32 ch (32 accs).
__global__ __launch_bounds__(256) void k_conv3(const float* __restrict__ b3, float* __restrict__ ws){
  const float* y2  = ws + OFF_Y2;
  const float* st  = ws + OFF_S2;
  const float* w3t = ws + OFF_W3T;
  float* y3 = ws + OFF_Y3;
  float* ps = ws + OFF_PS;
  float* pq = ws + OFF_PQ;
  int b = blockIdx.y;
  int blk = blockIdx.x;
  int l0 = blk*64;
  __shared__ float h[C2][66];
  __shared__ float sa[C2], sb[C2];
  if (threadIdx.x < C2){ sa[threadIdx.x]=st[threadIdx.x]; sb[threadIdx.x]=st[C2+threadIdx.x]; }
  __syncthreads();
  for (int idx=threadIdx.x; idx<C2*66; idx+=256){
    int i = idx/66, mm = idx - i*66;
    int m = mm + l0 - 1;
    float v=0.f;
    if (m>=0 && m<LEN3){
      const float* p = y2 + (b*C2+i)*LEN2 + 2*m;
      float v0 = fmaf(sa[i], p[0], sb[i]);
      float v1 = fmaf(sa[i], p[1], sb[i]);
      v = fmaxf(fmaxf(v0,v1), 0.f);
    }
    h[i][mm] = v;
  }
  __syncthreads();
  int grp  = __builtin_amdgcn_readfirstlane(threadIdx.x >> 6);  // 0..3, wave-uniform
  int lt   = threadIdx.x & 63;
  int cb   = grp * 32;
  const float* bb = b3 + cb;                    // wave-uniform
#define DECL3(c) float acc##c = bb[c];
  ACCS32(DECL3)
  for (int i=0;i<C2;i++){
    const float* wr = w3t + (i*3)*C3 + cb;      // wave-uniform; taps at +0, +C3, +2*C3
    float a0 = h[i][lt], a1 = h[i][lt+1], a2 = h[i][lt+2];
#define FMA3(c) acc##c = fmaf(wr[c],      a0, acc##c); \
                acc##c = fmaf(wr[C3+c],   a1, acc##c); \
                acc##c = fmaf(wr[2*C3+c], a2, acc##c);
    ACCS32(FMA3)
  }
  int l = l0 + lt;
  bool vL = (l < LEN3);
  float* yp = y3 + ((size_t)b*C3 + cb)*LEN3 + l;
#define ST3(c) if (vL) yp[c*LEN3] = acc##c;
  ACCS32(ST3)
  int pidx = b*8 + blk;
#define RD3(c) { float v_= vL ? acc##c : 0.f; \
                 float s_=v_; float q_=v_*v_; \
                 RED6(s_) RED6(q_) \
                 if (lt==0){ ps[(cb+c)*NPART + pidx]=s_; pq[(cb+c)*NPART + pidx]=q_; } }
  ACCS32(RD3)
}

// ---------------- K9: bn3+relu+mean ----------------
__global__ __launch_bounds__(256) void k_out(float* __restrict__ out, const float* __restrict__ ws){
  const float* y3 = ws + OFF_Y3;
  const float* st = ws + OFF_S3;
  int w = blockIdx.x*4 + (threadIdx.x>>6);
  int lane = threadIdx.x & 63;
  int b = w >> 7, c = w & 127;
  const float* p = y3 + (b*C3+c)*LEN3;
  float a = st[c], sh = st[C3+c];
  float s = 0.f;
  for (int i=lane; i<LEN3; i+=64) s += fmaxf(fmaf(a, p[i], sh), 0.f);
  #pragma unroll
  for (int off=32; off; off>>=1) s += __shfl_xor(s,off,64);
  if (lane==0) out[b*C3+c] = s * (1.0f/511.0f);
}

extern "C" void kernel_launch(void* const* d_in, const int* in_sizes, int n_in,
                              void* d_out, int out_size, void* d_ws, size_t ws_size,
                              hipStream_t stream) {
  const float* x   = (const float*)d_in[0];
  const float* c1w = (const float*)d_in[1];
  const float* c1b = (const float*)d_in[2];
  const float* w1  = (const float*)d_in[3];
  const float* b1  = (const float*)d_in[4];
  const float* g1  = (const float*)d_in[5];
  const float* be1 = (const float*)d_in[6];
  const float* w2  = (const float*)d_in[7];
  const float* b2  = (const float*)d_in[8];
  const float* g2  = (const float*)d_in[9];
  const float* be2 = (const float*)d_in[10];
  const float* w3  = (const float*)d_in[11];
  const float* b3  = (const float*)d_in[12];
  const float* g3  = (const float*)d_in[13];
  const float* be3 = (const float*)d_in[14];
  float* ws  = (float*)d_ws;
  float* out = (float*)d_out;

  hipLaunchKernelGGL(k_patch,  dim3(32,NB), dim3(256), 0, stream, x, ws);
  hipLaunchKernelGGL(k_initc2, dim3((NB*NP+255)/256), dim3(256), 0, stream, c1b, ws);
  hipLaunchKernelGGL(k_wt,     dim3((192*C3+255)/256), dim3(256), 0, stream, w2, w3, ws);
  hipLaunchKernelGGL(k_gemm,   dim3(32,4,8), dim3(256), 0, stream, c1w, ws);
  hipLaunchKernelGGL(k_conv1,  dim3(8,NB), dim3(256), 0, stream, w1, b1, ws);
  hipLaunchKernelGGL(k_stats,  dim3(NB,C1), dim3(256), 0, stream, ws+OFF_Y1, ws+OFF_PS, ws+OFF_PQ, C1, LEN1, NB);
  hipLaunchKernelGGL(k_fin,    dim3(C1), dim3(256), 0, stream, ws+OFF_PS, ws+OFF_PQ, g1, be1, ws+OFF_S1, C1, NB, 1.0/((double)NB*LEN1));
  hipLaunchKernelGGL(k_conv2,  dim3(8,NB), dim3(256), 0, stream, b2, ws);
  hipLaunchKernelGGL(k_fin,    dim3(C2), dim3(256), 0, stream, ws+OFF_PS, ws+OFF_PQ, g2, be2, ws+OFF_S2, C2, NPART, 1.0/((double)NB*LEN2));
  hipLaunchKernelGGL(k_conv3,  dim3(8,NB), dim3(256), 0, stream, b3, ws);
  hipLaunchKernelGGL(k_fin,    dim3(C3), dim3(256), 0, stream, ws+OFF_PS, ws+OFF_PQ, g3, be3, ws+OFF_S3, C3, NPART, 1.0/((double)NB*LEN3));
  hipLaunchKernelGGL(k_out,    dim3((NB*C3)/4), dim3(256), 0, stream, out, ws);
}

// Round 6
// 475.079 us; speedup vs baseline: 2.2809x; 1.0557x over previous
//
#include <hip/hip_runtime.h>
#include <math.h>

#define NB 256
#define SEQ 65536
#define NP 2047
#define NPM 2046
#define LEN1 2047
#define LEN2 1023
#define LEN3 511
#define C1 32
#define C2 64
#define C3 128
#define NPART 2048   // per-channel partial slots for fused stats (NB*8 blocks)

// workspace offsets (in floats)
#define OFF_X3   0
#define SZ_X3    (NB*3*NP)
#define OFF_DMAX (OFF_X3 + SZ_X3)
#define SZ_DMAX  (NB*NPM)
#define OFF_Y1   (OFF_DMAX + SZ_DMAX)
#define SZ_Y1    (NB*C1*LEN1)
#define OFF_Y2   (OFF_Y1 + SZ_Y1)
#define SZ_Y2    (NB*C2*LEN2)
#define OFF_PS   (OFF_Y2 + SZ_Y2)
#define OFF_PQ   (OFF_PS + C3*NPART)
#define OFF_S1   (OFF_PQ + C3*NPART)
#define OFF_S2   (OFF_S1 + 2*C1)
#define OFF_S3   (OFF_S2 + 2*C2)
#define OFF_W2T  (OFF_S3 + 2*C3)
#define OFF_W3T  (OFF_W2T + 96*C2)
#define OFF_Y3   OFF_Y1   // y1 dead after conv2; reuse for y3
#define OFF_WT   OFF_Y2   // W^T [NPM][NP] lives in Y2 region (dead until conv2)

// accumulators MUST be named scalars (arrays demoted badly in R1/R2)
#define ACCS16(X) X(0) X(1) X(2) X(3) X(4) X(5) X(6) X(7) \
                  X(8) X(9) X(10) X(11) X(12) X(13) X(14) X(15)
#define ACCS32(X) ACCS16(X) X(16) X(17) X(18) X(19) X(20) X(21) X(22) X(23) \
                  X(24) X(25) X(26) X(27) X(28) X(29) X(30) X(31)

#define RED6(v) v += __shfl_xor(v,32,64); v += __shfl_xor(v,16,64); \
                v += __shfl_xor(v, 8,64); v += __shfl_xor(v, 4,64); \
                v += __shfl_xor(v, 2,64); v += __shfl_xor(v, 1,64);

// ---------------- K1: patch mean/std + dmax (transposed) via 32-block partials ----------------
__global__ __launch_bounds__(256) void k_patch(const float* __restrict__ x, float* __restrict__ ws){
  float* x3    = ws + OFF_X3;
  float* dmaxT = ws + OFF_DMAX;        // [NPM][NB]
  int b = blockIdx.y;
  int chunk = blockIdx.x;              // 0..31, 2048 floats each
  const float* xr = x + (size_t)b*SEQ + chunk*2048;
  __shared__ float Ss[65], Qs[65], Dm[65];
  int w = threadIdx.x >> 6;
  int l = threadIdx.x & 63;
  #pragma unroll
  for (int i=0;i<2;i++){
    int seg = w*2 + i;                 // 0..7
    int off = seg*256;
    float4 A = *(const float4*)(xr + off + l*4);
    float4 Bh = make_float4(0.f,0.f,0.f,0.f);
    if (l >= 56){
      int g = chunk*2048 + off + 256 + (l-56)*4;
      if (g + 3 < SEQ) Bh = *(const float4*)(xr + off + 256 + (l-56)*4);
    }
    int src = (l+8) & 63;
    float p0 = __shfl(A.x, src, 64), p1 = __shfl(A.y, src, 64),
          p2 = __shfl(A.z, src, 64), p3 = __shfl(A.w, src, 64);
    if (l >= 56){ p0=Bh.x; p1=Bh.y; p2=Bh.z; p3=Bh.w; }
    float s = (A.x+A.y)+(A.z+A.w);
    float q = fmaf(A.x,A.x, fmaf(A.y,A.y, fmaf(A.z,A.z, A.w*A.w)));
    float d = fmaxf(fmaxf(p0-A.x, p1-A.y), fmaxf(p2-A.z, p3-A.w));
    #pragma unroll
    for (int o=1;o<8;o<<=1){
      s += __shfl_xor(s,o,64);
      q += __shfl_xor(q,o,64);
      d  = fmaxf(d, __shfl_xor(d,o,64));
    }
    if ((l&7)==0){ int m = seg*8 + (l>>3); Ss[m]=s; Qs[m]=q; Dm[m]=d; }
  }
  if (w==0){                            // halo: 32-block index 64 of this chunk
    float s=0.f,q=0.f,d=-1e30f;
    if (l < 8){
      int g = chunk*2048 + 2048 + l*4;
      if (g+3 < SEQ){
        float4 A = *(const float4*)(xr + 2048 + l*4);
        float4 P = make_float4(0.f,0.f,0.f,0.f);
        if (g+35 < SEQ) P = *(const float4*)(xr + 2048 + 32 + l*4);
        s = (A.x+A.y)+(A.z+A.w);
        q = fmaf(A.x,A.x, fmaf(A.y,A.y, fmaf(A.z,A.z, A.w*A.w)));
        d = fmaxf(fmaxf(P.x-A.x, P.y-A.y), fmaxf(P.z-A.z, P.w-A.w));
      }
    }
    #pragma unroll
    for (int o=1;o<8;o<<=1){
      s += __shfl_xor(s,o,64);
      q += __shfl_xor(q,o,64);
      d  = fmaxf(d, __shfl_xor(d,o,64));
    }
    if (l==0){ Ss[64]=s; Qs[64]=q; Dm[64]=d; }
  }
  __syncthreads();
  if (threadIdx.x < 64){
    int j = threadIdx.x;
    int p = chunk*64 + j;
    if (p < NP){
      float S = Ss[j]+Ss[j+1];
      float Q = Qs[j]+Qs[j+1];
      float mean = S*(1.0f/64.0f);
      float var  = (Q - S*mean)*(1.0f/63.0f);   // ddof=1
      x3[(b*3+0)*NP + p] = mean;
      x3[(b*3+1)*NP + p] = sqrtf(fmaxf(var,0.0f));
      if (p < NPM) dmaxT[(size_t)p*NB + b] = fmaxf(Dm[j], Dm[j+1]);  // L2-resident (2MB)
    }
  }
}

// ---------------- K0: init x3 channel 2 with conv1_b ----------------
__global__ __launch_bounds__(256) void k_initc2(const float* __restrict__ c1b, float* __restrict__ ws){
  int i = blockIdx.x*256 + threadIdx.x;
  if (i < NB*NP){
    int b = i / NP; int o = i - b*NP;
    ws[OFF_X3 + (b*3+2)*NP + o] = c1b[o];
  }
}

// ---------------- K_trW: conv1_w [NP][NPM] -> Wt [NPM][NP] ----------------
__global__ __launch_bounds__(256) void k_trW(const float* __restrict__ W, float* __restrict__ ws){
  float* Wt = ws + OFF_WT;
  __shared__ float t[64][65];
  int ko = blockIdx.x*64;   // k tile base (NPM dim)
  int oo = blockIdx.y*64;   // o tile base (NP dim)
  int tx = threadIdx.x & 63, tw = threadIdx.x >> 6;
  #pragma unroll
  for (int r=0;r<16;r++){
    int rr = tw*16 + r;
    int o = oo + rr, k = ko + tx;
    t[rr][tx] = (o < NP && k < NPM) ? W[(size_t)o*NPM + k] : 0.f;
  }
  __syncthreads();
  #pragma unroll
  for (int r=0;r<16;r++){
    int rr = tw*16 + r;
    int k = ko + rr, o = oo + tx;
    if (k < NPM && o < NP) Wt[(size_t)k*NP + o] = t[tx][rr];
  }
}

// ---------------- K_wt: transpose conv weights to [i*3+tap][c] ----------------
__global__ __launch_bounds__(256) void k_wt(const float* __restrict__ w2, const float* __restrict__ w3, float* __restrict__ ws){
  float* w2t = ws + OFF_W2T;
  float* w3t = ws + OFF_W3T;
  int t = blockIdx.x*256 + threadIdx.x;
  if (t < 96*C2){
    int r = t / C2, c = t - r*C2;
    int i = r/3, tap = r - i*3;
    w2t[t] = w2[(c*C1+i)*3 + tap];
  }
  if (t < 192*C3){
    int r = t / C3, c = t - r*C3;
    int i = r/3, tap = r - i*3;
    w3t[t] = w3[(c*C2+i)*3 + tap];
  }
}

// ---------------- K2: d2[b,o] += sum_k At[k,b]*Wt[k,o]  (no LDS, no barriers) ----------------
// lanes = o (coalesced W load); 4 waves x 32 b named-scalar accs; A via s_load_dwordx16.
__global__ __launch_bounds__(256) void k_gemm(float* __restrict__ ws){
  const float* At = ws + OFF_DMAX;   // [NPM][NB]
  const float* Wt = ws + OFF_WT;     // [NPM][NP]
  float* x3 = ws + OFF_X3;
  int o  = blockIdx.x*64 + (threadIdx.x & 63);
  int w  = __builtin_amdgcn_readfirstlane(threadIdx.x >> 6);
  int bg = blockIdx.y*128 + w*32;    // wave-uniform b-group
  int ks = blockIdx.z*256;
  int ke = min(ks+256, NPM);
  int oL = min(o, NP-1);
#define DG(c) float acc##c = 0.f;
  ACCS32(DG)
  const float* wp = Wt + oL;
  #pragma unroll 2
  for (int k=ks; k<ke; ++k){
    float wv = wp[(size_t)k*NP];
    const float* ar = At + (size_t)k*NB + bg;   // wave-uniform -> s_load_dwordx16 x2
#define FG(c) acc##c = fmaf(ar[c], wv, acc##c);
    ACCS32(FG)
  }
  if (o < NP){
    float* xp = x3 + 2*NP + o;
#define SG(c) atomicAdd(xp + (size_t)(bg+c)*3*NP, acc##c);
    ACCS32(SG)
  }
}

// ---------------- K3: conv1 (3->32, k=5, pad=2) ----------------
__global__ __launch_bounds__(256) void k_conv1(const float* __restrict__ w1, const float* __restrict__ b1, float* __restrict__ ws){
  const float* x3 = ws + OFF_X3;
  float* y1 = ws + OFF_Y1;
  int b = blockIdx.y;
  int l = blockIdx.x*256 + threadIdx.x;
  bool valid = (l < LEN1);
  float xin[3][5];
  #pragma unroll
  for (int i=0;i<3;i++){
    #pragma unroll
    for (int j=0;j<5;j++){
      int t = l + j - 2;
      xin[i][j] = (valid && t >= 0 && t < LEN1) ? x3[(b*3+i)*NP + t] : 0.f;
    }
  }
  #pragma unroll 8
  for (int c=0;c<C1;c++){
    float a = b1[c];
    #pragma unroll
    for (int i=0;i<3;i++){
      #pragma unroll
      for (int j=0;j<5;j++) a = fmaf(w1[(c*3+i)*5+j], xin[i][j], a);
    }
    if (valid) y1[(b*C1+c)*LEN1 + l] = a;
  }
}

// ---------------- stats (layer1 only): per-(b,c) sum/sumsq ----------------
__global__ __launch_bounds__(256) void k_stats(const float* __restrict__ y, float* __restrict__ ps,
                                               float* __restrict__ pq, int C, int L, int npart){
  int b = blockIdx.x, c = blockIdx.y;
  const float* p = y + ((size_t)b*C + c)*L;
  float s=0.f, q=0.f;
  for (int i=threadIdx.x; i<L; i+=256){ float v=p[i]; s+=v; q=fmaf(v,v,q); }
  __shared__ float rs[4], rq[4];
  RED6(s) RED6(q)
  int wid = threadIdx.x>>6, lane = threadIdx.x&63;
  if (lane==0){ rs[wid]=s; rq[wid]=q; }
  __syncthreads();
  if (threadIdx.x==0){
    ps[c*npart + b] = rs[0]+rs[1]+rs[2]+rs[3];
    pq[c*npart + b] = rq[0]+rq[1]+rq[2]+rq[3];
  }
}

// ---------------- finalize BN from partials ----------------
__global__ __launch_bounds__(256) void k_fin(const float* __restrict__ ps, const float* __restrict__ pq,
                                             const float* __restrict__ g, const float* __restrict__ be,
                                             float* __restrict__ stats, int C, int npart, double invN){
  int c = blockIdx.x;
  double s=0.0, q=0.0;
  for (int j=threadIdx.x; j<npart; j+=256){ s += (double)ps[c*npart+j]; q += (double)pq[c*npart+j]; }
  #pragma unroll
  for (int off=32; off; off>>=1){ s += __shfl_xor(s,off,64); q += __shfl_xor(q,off,64); }
  __shared__ double rs[4], rq[4];
  int wid = threadIdx.x>>6, lane=threadIdx.x&63;
  if (lane==0){ rs[wid]=s; rq[wid]=q; }
  __syncthreads();
  if (threadIdx.x==0){
    double S = rs[0]+rs[1]+rs[2]+rs[3];
    double Q = rq[0]+rq[1]+rq[2]+rq[3];
    double mean = S*invN;
    double var  = Q*invN - mean*mean;
    double a = (double)g[c] / sqrt(var + 1e-5);
    stats[c]   = (float)a;
    stats[C+c] = (float)((double)be[c] - mean*a);
  }
}

// ---------------- K5: bn1+relu+pool + conv2 (32->64, k=3, pad=1) + fused stats ----------------
__global__ __launch_bounds__(256) void k_conv2(const float* __restrict__ b2, float* __restrict__ ws){
  const float* y1  = ws + OFF_Y1;
  const float* st  = ws + OFF_S1;
  const float* w2t = ws + OFF_W2T;
  float* y2 = ws + OFF_Y2;
  float* ps = ws + OFF_PS;
  float* pq = ws + OFF_PQ;
  int b = blockIdx.y;
  int blk = blockIdx.x;
  int l0 = blk*128;
  __shared__ float h[C1][130];
  __shared__ float sa[C1], sb[C1];
  if (threadIdx.x < C1){ sa[threadIdx.x]=st[threadIdx.x]; sb[threadIdx.x]=st[C1+threadIdx.x]; }
  __syncthreads();
  for (int idx=threadIdx.x; idx<C1*130; idx+=256){
    int i = idx/130, mm = idx - i*130;
    int m = mm + l0 - 1;
    float v = 0.f;
    if (m>=0 && m<LEN2){
      const float* p = y1 + (b*C1+i)*LEN1 + 2*m;
      float v0 = fmaf(sa[i], p[0], sb[i]);
      float v1 = fmaf(sa[i], p[1], sb[i]);
      v = fmaxf(fmaxf(v0,v1), 0.f);
    }
    h[i][mm] = v;
  }
  __syncthreads();
  int grp  = __builtin_amdgcn_readfirstlane(threadIdx.x >> 6);
  int lt   = threadIdx.x & 63;
  int cb   = grp * 16;
  const float* bb = b2 + cb;
#define DECL2(c) float accA##c = bb[c]; float accB##c = accA##c;
  ACCS16(DECL2)
  for (int i=0;i<C1;i++){
    const float* wr = w2t + (i*3)*C2 + cb;
    float a0 = h[i][lt],    a1 = h[i][lt+1],  a2 = h[i][lt+2];
    float p0 = h[i][lt+64], p1 = h[i][lt+65], p2 = h[i][lt+66];
#define FMA2(c) { float w0_=wr[c], w1_=wr[C2+c], w2_=wr[2*C2+c]; \
                  accA##c = fmaf(w0_, a0, accA##c); accA##c = fmaf(w1_, a1, accA##c); accA##c = fmaf(w2_, a2, accA##c); \
                  accB##c = fmaf(w0_, p0, accB##c); accB##c = fmaf(w1_, p1, accB##c); accB##c = fmaf(w2_, p2, accB##c); }
    ACCS16(FMA2)
  }
  int lA = l0 + lt, lB = lA + 64;
  bool vB = (lB < LEN2);
  float* yp = y2 + ((size_t)b*C2 + cb)*LEN2 + lA;
#define ST2(c) { yp[c*LEN2] = accA##c; if (vB) yp[c*LEN2+64] = accB##c; }
  ACCS16(ST2)
  int pidx = b*8 + blk;
#define RD2(c) { float vA_=accA##c, vb_=vB?accB##c:0.f; \
                 float s_=vA_+vb_; float q_=fmaf(vA_,vA_, vb_*vb_); \
                 RED6(s_) RED6(q_) \
                 if (lt==0){ ps[(cb+c)*NPART + pidx]=s_; pq[(cb+c)*NPART + pidx]=q_; } }
  ACCS16(RD2)
}

// ---------------- K7: bn2+relu+pool + conv3 (64->128, k=3, pad=1) + fused stats ----------------
__global__ __launch_bounds__(256) void k_conv3(const float* __restrict__ b3, float* __restrict__ ws){
  const float* y2  = ws + OFF_Y2;
  const float* st  = ws + OFF_S2;
  const float* w3t = ws + OFF_W3T;
  float* y3 = ws + OFF_Y3;
  float* ps = ws + OFF_PS;
  float* pq = ws + OFF_PQ;
  int b = blockIdx.y;
  int blk = blockIdx.x;
  int l0 = blk*64;
  __shared__ float h[C2][66];
  __shared__ float sa[C2], sb[C2];
  if (threadIdx.x < C2){ sa[threadIdx.x]=st[threadIdx.x]; sb[threadIdx.x]=st[C2+threadIdx.x]; }
  __syncthreads();
  for (int idx=threadIdx.x; idx<C2*66; idx+=256){
    int i = idx/66, mm = idx - i*66;
    int m = mm + l0 - 1;
    float v=0.f;
    if (m>=0 && m<LEN3){
      const float* p = y2 + (b*C2+i)*LEN2 + 2*m;
      float v0 = fmaf(sa[i], p[0], sb[i]);
      float v1 = fmaf(sa[i], p[1], sb[i]);
      v = fmaxf(fmaxf(v0,v1), 0.f);
    }
    h[i][mm] = v;
  }
  __syncthreads();
  int grp  = __builtin_amdgcn_readfirstlane(threadIdx.x >> 6);
  int lt   = threadIdx.x & 63;
  int cb   = grp * 32;
  const float* bb = b3 + cb;
#define DECL3(c) float acc##c = bb[c];
  ACCS32(DECL3)
  for (int i=0;i<C2;i++){
    const float* wr = w3t + (i*3)*C3 + cb;
    float a0 = h[i][lt], a1 = h[i][lt+1], a2 = h[i][lt+2];
#define FMA3(c) acc##c = fmaf(wr[c],      a0, acc##c); \
                acc##c = fmaf(wr[C3+c],   a1, acc##c); \
                acc##c = fmaf(wr[2*C3+c], a2, acc##c);
    ACCS32(FMA3)
  }
  int l = l0 + lt;
  bool vL = (l < LEN3);
  float* yp = y3 + ((size_t)b*C3 + cb)*LEN3 + l;
#define ST3(c) if (vL) yp[c*LEN3] = acc##c;
  ACCS32(ST3)
  int pidx = b*8 + blk;
#define RD3(c) { float v_= vL ? acc##c : 0.f; \
                 float s_=v_; float q_=v_*v_; \
                 RED6(s_) RED6(q_) \
                 if (lt==0){ ps[(cb+c)*NPART + pidx]=s_; pq[(cb+c)*NPART + pidx]=q_; } }
  ACCS32(RD3)
}

// ---------------- K9: bn3+relu+mean ----------------
__global__ __launch_bounds__(256) void k_out(float* __restrict__ out, const float* __restrict__ ws){
  const float* y3 = ws + OFF_Y3;
  const float* st = ws + OFF_S3;
  int w = blockIdx.x*4 + (threadIdx.x>>6);
  int lane = threadIdx.x & 63;
  int b = w >> 7, c = w & 127;
  const float* p = y3 + (b*C3+c)*LEN3;
  float a = st[c], sh = st[C3+c];
  float s = 0.f;
  for (int i=lane; i<LEN3; i+=64) s += fmaxf(fmaf(a, p[i], sh), 0.f);
  #pragma unroll
  for (int off=32; off; off>>=1) s += __shfl_xor(s,off,64);
  if (lane==0) out[b*C3+c] = s * (1.0f/511.0f);
}

extern "C" void kernel_launch(void* const* d_in, const int* in_sizes, int n_in,
                              void* d_out, int out_size, void* d_ws, size_t ws_size,
                              hipStream_t stream) {
  const float* x   = (const float*)d_in[0];
  const float* c1w = (const float*)d_in[1];
  const float* c1b = (const float*)d_in[2];
  const float* w1  = (const float*)d_in[3];
  const float* b1  = (const float*)d_in[4];
  const float* g1  = (const float*)d_in[5];
  const float* be1 = (const float*)d_in[6];
  const float* w2  = (const float*)d_in[7];
  const float* b2  = (const float*)d_in[8];
  const float* g2  = (const float*)d_in[9];
  const float* be2 = (const float*)d_in[10];
  const float* w3  = (const float*)d_in[11];
  const float* b3  = (const float*)d_in[12];
  const float* g3  = (const float*)d_in[13];
  const float* be3 = (const float*)d_in[14];
  float* ws  = (float*)d_ws;
  float* out = (float*)d_out;

  hipLaunchKernelGGL(k_patch,  dim3(32,NB), dim3(256), 0, stream, x, ws);
  hipLaunchKernelGGL(k_initc2, dim3((NB*NP+255)/256), dim3(256), 0, stream, c1b, ws);
  hipLaunchKernelGGL(k_trW,    dim3(32,32), dim3(256), 0, stream, c1w, ws);
  hipLaunchKernelGGL(k_wt,     dim3((192*C3+255)/256), dim3(256), 0, stream, w2, w3, ws);
  hipLaunchKernelGGL(k_gemm,   dim3(32,2,8), dim3(256), 0, stream, ws);
  hipLaunchKernelGGL(k_conv1,  dim3(8,NB), dim3(256), 0, stream, w1, b1, ws);
  hipLaunchKernelGGL(k_stats,  dim3(NB,C1), dim3(256), 0, stream, ws+OFF_Y1, ws+OFF_PS, ws+OFF_PQ, C1, LEN1, NB);
  hipLaunchKernelGGL(k_fin,    dim3(C1), dim3(256), 0, stream, ws+OFF_PS, ws+OFF_PQ, g1, be1, ws+OFF_S1, C1, NB, 1.0/((double)NB*LEN1));
  hipLaunchKernelGGL(k_conv2,  dim3(8,NB), dim3(256), 0, stream, b2, ws);
  hipLaunchKernelGGL(k_fin,    dim3(C2), dim3(256), 0, stream, ws+OFF_PS, ws+OFF_PQ, g2, be2, ws+OFF_S2, C2, NPART, 1.0/((double)NB*LEN2));
  hipLaunchKernelGGL(k_conv3,  dim3(8,NB), dim3(256), 0, stream, b3, ws);
  hipLaunchKernelGGL(k_fin,    dim3(C3), dim3(256), 0, stream, ws+OFF_PS, ws+OFF_PQ, g3, be3, ws+OFF_S3, C3, NPART, 1.0/((double)NB*LEN3));
  hipLaunchKernelGGL(k_out,    dim3((NB*C3)/4), dim3(256), 0, stream, out, ws);
}